// Round 1
// baseline (1439.689 us; speedup 1.0000x reference)
//
#include <hip/hip_runtime.h>
#include <math.h>

#define BB 2
#define NN 6
#define DDIM 128
#define MM 625
#define HH 28
#define WWW 60
#define HWSZ (HH*WWW)        // 1680
#define NQ (NN*MM)           // 3750
#define NK (NN*HWSZ)         // 10080
#define HEADS 4
#define DHEAD 32
#define EPSV 1e-5f
#define KC 4
#define KCHUNK 2560
#define NQT 59               // ceil(3750/64)

// ---- workspace offsets (floats) ----
#define OFF_QH   0            // 960000   (aliased by z0 later)
#define OFF_KH   960000       // 2580480  (aliased by zn later)
#define OFF_VH   3540480      // 2580480  (aliased by hmid later)
#define OFF_PACC 6120960      // 3840000
#define OFF_PM   9960960      // 120000
#define OFF_PL   10080960     // 120000
#define OFF_A    10200960     // 960000
#define OFF_Z0   0
#define OFF_ZN   960000
#define OFF_HMID 3540480

// LN (over 128 channels, channel-strided input) + 128x128 projection + bias.
// Input x layout: (B*N, 128, S) i.e. addr = (bn*128+dd)*S + s ; row g = bn*S+s.
__global__ void __launch_bounds__(128) k_lnproj(const float* __restrict__ x, int S, int rows,
        const float* __restrict__ gam, const float* __restrict__ bet,
        const float* __restrict__ Wt, const float* __restrict__ bias,
        float* __restrict__ outp) {
    __shared__ float xs[32][132];
    __shared__ float smu[32], srs[32];
    const int t = threadIdx.x;
    const int g0 = blockIdx.x * 32;
    // phase A: transposed coalesced load (lanes sweep spatial index)
    {
        const int sl = t & 31, du = t >> 5;
        const int grow = g0 + sl;
        const bool vload = grow < rows;
        const int bn = grow / S, ss = grow % S;
        const float* xbase = x + (size_t)bn * 128 * S + ss;
        for (int it = 0; it < 32; ++it) {
            int dd = it * 4 + du;
            xs[sl][dd] = vload ? xbase[(size_t)dd * S] : 0.f;
        }
    }
    __syncthreads();
    // phase B: per-row stats (4 threads per row, shuffle-reduce)
    {
        const int r = t >> 2, p = t & 3;
        float sum = 0.f, sq = 0.f;
        for (int j = 0; j < 32; ++j) {
            float v = xs[r][p + 4 * j];
            sum += v; sq += v * v;
        }
        sum += __shfl_xor(sum, 1); sq += __shfl_xor(sq, 1);
        sum += __shfl_xor(sum, 2); sq += __shfl_xor(sq, 2);
        if (p == 0) {
            float mu = sum * (1.f / 128.f);
            float var = sq * (1.f / 128.f) - mu * mu;
            smu[r] = mu;
            srs[r] = rsqrtf(var + EPSV);
        }
    }
    __syncthreads();
    // phase C: normalize in LDS
    {
        const float gv = gam[t], bv = bet[t];
        for (int rr = 0; rr < 32; ++rr)
            xs[rr][t] = (xs[rr][t] - smu[rr]) * srs[rr] * gv + bv;
    }
    __syncthreads();
    // phase D: GEMM, thread owns output channel c=t
    float acc[32];
    #pragma unroll
    for (int rr = 0; rr < 32; ++rr) acc[rr] = 0.f;
    for (int d4 = 0; d4 < 32; ++d4) {
        const float w0 = Wt[(d4 * 4 + 0) * 128 + t];
        const float w1 = Wt[(d4 * 4 + 1) * 128 + t];
        const float w2 = Wt[(d4 * 4 + 2) * 128 + t];
        const float w3 = Wt[(d4 * 4 + 3) * 128 + t];
        #pragma unroll
        for (int rr = 0; rr < 32; ++rr) {
            float4 xv = *(const float4*)&xs[rr][d4 * 4];
            acc[rr] += xv.x * w0 + xv.y * w1 + xv.z * w2 + xv.w * w3;
        }
    }
    const float bb = bias[t];
    for (int rr = 0; rr < 32; ++rr) {
        int grow = g0 + rr;
        if (grow < rows) outp[(size_t)grow * 128 + t] = acc[rr] + bb;
    }
}

// flash attention partial: one wave per block, thread owns one query.
__global__ void __launch_bounds__(64) k_attn_partial(const float* __restrict__ qh,
        const float* __restrict__ kh, const float* __restrict__ vh,
        float* __restrict__ pacc, float* __restrict__ pm, float* __restrict__ pl) {
    __shared__ float Ks[32][32];
    __shared__ float Vs[32][32];
    const int t = threadIdx.x;
    const int bid = blockIdx.x;
    const int bh = bid / (NQT * KC);
    const int rem = bid % (NQT * KC);
    const int qt = rem / KC;
    const int kc = rem % KC;
    const int b = bh / HEADS, h = bh % HEADS;
    const int qq = qt * 64 + t;
    const bool valid = qq < NQ;
    const float scale = 0.17677669529663687f; // 1/sqrt(32)
    float qreg[32];
    if (valid) {
        const float4* qp = (const float4*)(qh + ((size_t)b * NQ + qq) * 128 + h * 32);
        #pragma unroll
        for (int j = 0; j < 8; ++j) {
            float4 v = qp[j];
            qreg[4*j+0] = v.x * scale; qreg[4*j+1] = v.y * scale;
            qreg[4*j+2] = v.z * scale; qreg[4*j+3] = v.w * scale;
        }
    } else {
        #pragma unroll
        for (int j = 0; j < 32; ++j) qreg[j] = 0.f;
    }
    float m = -INFINITY, l = 0.f;
    float acc[32];
    #pragma unroll
    for (int j = 0; j < 32; ++j) acc[j] = 0.f;

    const int kstart = kc * KCHUNK;
    const int kend = (kstart + KCHUNK < NK) ? (kstart + KCHUNK) : NK;
    const float* kbase = kh + (size_t)b * NK * 128 + h * 32;
    const float* vbase = vh + (size_t)b * NK * 128 + h * 32;
    for (int k0 = kstart; k0 < kend; k0 += 32) {
        __syncthreads();
        #pragma unroll
        for (int i = 0; i < 4; ++i) {
            int f = t + 64 * i;
            int kk = f >> 3, jj = (f & 7) * 4;
            *(float4*)&Ks[kk][jj] = *(const float4*)(kbase + (size_t)(k0 + kk) * 128 + jj);
            *(float4*)&Vs[kk][jj] = *(const float4*)(vbase + (size_t)(k0 + kk) * 128 + jj);
        }
        __syncthreads();
        float s[32];
        #pragma unroll
        for (int kk = 0; kk < 32; ++kk) {
            float dot = 0.f;
            #pragma unroll
            for (int j4 = 0; j4 < 8; ++j4) {
                float4 kv = *(const float4*)&Ks[kk][j4 * 4];
                dot += qreg[4*j4] * kv.x + qreg[4*j4+1] * kv.y
                     + qreg[4*j4+2] * kv.z + qreg[4*j4+3] * kv.w;
            }
            s[kk] = dot;
        }
        float mt = s[0];
        #pragma unroll
        for (int kk = 1; kk < 32; ++kk) mt = fmaxf(mt, s[kk]);
        const float mnew = fmaxf(m, mt);
        const float resc = __expf(m - mnew);
        l *= resc;
        #pragma unroll
        for (int j = 0; j < 32; ++j) acc[j] *= resc;
        #pragma unroll
        for (int kk = 0; kk < 32; ++kk) {
            float w = __expf(s[kk] - mnew);
            l += w;
            #pragma unroll
            for (int j4 = 0; j4 < 8; ++j4) {
                float4 vv = *(const float4*)&Vs[kk][j4 * 4];
                acc[4*j4+0] += w * vv.x; acc[4*j4+1] += w * vv.y;
                acc[4*j4+2] += w * vv.z; acc[4*j4+3] += w * vv.w;
            }
        }
        m = mnew;
    }
    if (valid) {
        const size_t pi = (size_t)(bh * KC + kc) * NQ + qq;
        float4* po = (float4*)(pacc + pi * 32);
        #pragma unroll
        for (int j4 = 0; j4 < 8; ++j4)
            po[j4] = make_float4(acc[4*j4], acc[4*j4+1], acc[4*j4+2], acc[4*j4+3]);
        pm[pi] = m; pl[pi] = l;
    }
}

__global__ void __launch_bounds__(256) k_attn_combine(const float* __restrict__ pacc,
        const float* __restrict__ pm, const float* __restrict__ pl,
        float* __restrict__ a) {
    const int idx = blockIdx.x * 256 + threadIdx.x;  // B*HEADS*NQ*32 total, exact
    const int j = idx & 31;
    const int qq = (idx >> 5) % NQ;
    const int bh = idx / (32 * NQ);
    const int b = bh / HEADS, h = bh % HEADS;
    const size_t base = (size_t)bh * KC * NQ + qq;
    float mM = -INFINITY;
    #pragma unroll
    for (int kc = 0; kc < KC; ++kc) mM = fmaxf(mM, pm[base + (size_t)kc * NQ]);
    float L = 0.f, val = 0.f;
    #pragma unroll
    for (int kc = 0; kc < KC; ++kc) {
        size_t pi = base + (size_t)kc * NQ;
        float e = __expf(pm[pi] - mM);
        L += pl[pi] * e;
        val += pacc[pi * 32 + j] * e;
    }
    a[((size_t)b * NQ + qq) * 128 + h * 32 + j] = val / L;
}

// out-projection: z0 = a @ proj_w + proj_b  (row-contiguous input)
__global__ void __launch_bounds__(128) k_gemm_a(const float* __restrict__ a,
        const float* __restrict__ Wt, const float* __restrict__ bias,
        float* __restrict__ z0) {
    __shared__ float xs[32][132];
    const int t = threadIdx.x;
    const int g0 = blockIdx.x * 32;
    for (int rr = 0; rr < 32; ++rr) {
        int grow = g0 + rr;
        xs[rr][t] = (grow < BB * NQ) ? a[(size_t)grow * 128 + t] : 0.f;
    }
    __syncthreads();
    float acc[32];
    #pragma unroll
    for (int rr = 0; rr < 32; ++rr) acc[rr] = 0.f;
    for (int d4 = 0; d4 < 32; ++d4) {
        const float w0 = Wt[(d4 * 4 + 0) * 128 + t];
        const float w1 = Wt[(d4 * 4 + 1) * 128 + t];
        const float w2 = Wt[(d4 * 4 + 2) * 128 + t];
        const float w3 = Wt[(d4 * 4 + 3) * 128 + t];
        #pragma unroll
        for (int rr = 0; rr < 32; ++rr) {
            float4 xv = *(const float4*)&xs[rr][d4 * 4];
            acc[rr] += xv.x * w0 + xv.y * w1 + xv.z * w2 + xv.w * w3;
        }
    }
    const float bb = bias[t];
    for (int rr = 0; rr < 32; ++rr) {
        int grow = g0 + rr;
        if (grow < BB * NQ) z0[(size_t)grow * 128 + t] = acc[rr] + bb;
    }
}

// z0 + skip (channel-strided) -> pre-LN -> zn
__global__ void __launch_bounds__(128) k_skip_ln(const float* __restrict__ z0,
        const float* __restrict__ skip,
        const float* __restrict__ gam, const float* __restrict__ bet,
        float* __restrict__ zn) {
    __shared__ float xs[32][132];
    __shared__ float smu[32], srs[32];
    const int t = threadIdx.x;
    const int g0 = blockIdx.x * 32;
    for (int rr = 0; rr < 32; ++rr) {
        int grow = g0 + rr;
        xs[rr][t] = (grow < BB * NQ) ? z0[(size_t)grow * 128 + t] : 0.f;
    }
    __syncthreads();
    {
        const int sl = t & 31, du = t >> 5;
        const int grow = g0 + sl;
        if (grow < BB * NQ) {
            const int bn = grow / MM, mm = grow % MM;
            const float* sbase = skip + (size_t)bn * 128 * MM + mm;
            for (int it = 0; it < 32; ++it) {
                int dd = it * 4 + du;
                xs[sl][dd] += sbase[(size_t)dd * MM];
            }
        }
    }
    __syncthreads();
    {
        const int r = t >> 2, p = t & 3;
        float sum = 0.f, sq = 0.f;
        for (int j = 0; j < 32; ++j) {
            float v = xs[r][p + 4 * j];
            sum += v; sq += v * v;
        }
        sum += __shfl_xor(sum, 1); sq += __shfl_xor(sq, 1);
        sum += __shfl_xor(sum, 2); sq += __shfl_xor(sq, 2);
        if (p == 0) {
            float mu = sum * (1.f / 128.f);
            float var = sq * (1.f / 128.f) - mu * mu;
            smu[r] = mu;
            srs[r] = rsqrtf(var + EPSV);
        }
    }
    __syncthreads();
    const float gv = gam[t], bv = bet[t];
    for (int rr = 0; rr < 32; ++rr) {
        int grow = g0 + rr;
        if (grow < BB * NQ)
            zn[(size_t)grow * 128 + t] = (xs[rr][t] - smu[rr]) * srs[rr] * gv + bv;
    }
}

// hmid = gelu(zn @ w1 + b1), 128->256
__global__ void __launch_bounds__(256) k_mlp1(const float* __restrict__ zn,
        const float* __restrict__ W1, const float* __restrict__ b1,
        float* __restrict__ hmid) {
    __shared__ float xs[32][132];
    const int t = threadIdx.x;
    const int g0 = blockIdx.x * 32;
    for (int it = 0; it < 16; ++it) {
        int rr = it * 2 + (t >> 7);
        int cc = t & 127;
        int grow = g0 + rr;
        xs[rr][cc] = (grow < BB * NQ) ? zn[(size_t)grow * 128 + cc] : 0.f;
    }
    __syncthreads();
    float acc[32];
    #pragma unroll
    for (int rr = 0; rr < 32; ++rr) acc[rr] = 0.f;
    for (int d4 = 0; d4 < 32; ++d4) {
        const float w0 = W1[(d4 * 4 + 0) * 256 + t];
        const float w1 = W1[(d4 * 4 + 1) * 256 + t];
        const float w2 = W1[(d4 * 4 + 2) * 256 + t];
        const float w3 = W1[(d4 * 4 + 3) * 256 + t];
        #pragma unroll
        for (int rr = 0; rr < 32; ++rr) {
            float4 xv = *(const float4*)&xs[rr][d4 * 4];
            acc[rr] += xv.x * w0 + xv.y * w1 + xv.z * w2 + xv.w * w3;
        }
    }
    const float bb = b1[t];
    for (int rr = 0; rr < 32; ++rr) {
        int grow = g0 + rr;
        if (grow < BB * NQ) {
            float x = acc[rr] + bb;
            hmid[(size_t)grow * 256 + t] = 0.5f * x * (1.f + erff(x * 0.70710678118654752f));
        }
    }
}

// z2 = zn + hmid @ w2 + b2 ; post-LN ; transposed write to out (B,N,128,M)
__global__ void __launch_bounds__(128) k_mlp2(const float* __restrict__ hmid,
        const float* __restrict__ zn,
        const float* __restrict__ W2, const float* __restrict__ b2,
        const float* __restrict__ gam, const float* __restrict__ bet,
        float* __restrict__ outp) {
    __shared__ float hs[32][260];      // also reused as zt[32][132]
    __shared__ float smu[32], srs[32];
    const int t = threadIdx.x;
    const int g0 = blockIdx.x * 32;
    for (int it = 0; it < 64; ++it) {
        int rr = it >> 1;
        int cc = (it & 1) * 128 + t;
        int grow = g0 + rr;
        hs[rr][cc] = (grow < BB * NQ) ? hmid[(size_t)grow * 256 + cc] : 0.f;
    }
    __syncthreads();
    float acc[32];
    #pragma unroll
    for (int rr = 0; rr < 32; ++rr) acc[rr] = 0.f;
    for (int d4 = 0; d4 < 64; ++d4) {
        const float w0 = W2[(d4 * 4 + 0) * 128 + t];
        const float w1 = W2[(d4 * 4 + 1) * 128 + t];
        const float w2 = W2[(d4 * 4 + 2) * 128 + t];
        const float w3 = W2[(d4 * 4 + 3) * 128 + t];
        #pragma unroll
        for (int rr = 0; rr < 32; ++rr) {
            float4 hv = *(const float4*)&hs[rr][d4 * 4];
            acc[rr] += hv.x * w0 + hv.y * w1 + hv.z * w2 + hv.w * w3;
        }
    }
    __syncthreads();   // done reading hs; reuse as zt
    float* zt = &hs[0][0];
    const float bb = b2[t];
    for (int rr = 0; rr < 32; ++rr) {
        int grow = g0 + rr;
        float zv = (grow < BB * NQ) ? zn[(size_t)grow * 128 + t] : 0.f;
        zt[rr * 132 + t] = zv + acc[rr] + bb;
    }
    __syncthreads();
    {
        const int r = t >> 2, p = t & 3;
        float sum = 0.f, sq = 0.f;
        for (int j = 0; j < 32; ++j) {
            float v = zt[r * 132 + p + 4 * j];
            sum += v; sq += v * v;
        }
        sum += __shfl_xor(sum, 1); sq += __shfl_xor(sq, 1);
        sum += __shfl_xor(sum, 2); sq += __shfl_xor(sq, 2);
        if (p == 0) {
            float mu = sum * (1.f / 128.f);
            float var = sq * (1.f / 128.f) - mu * mu;
            smu[r] = mu;
            srs[r] = rsqrtf(var + EPSV);
        }
    }
    __syncthreads();
    {
        const int sl = t & 31, du = t >> 5;
        const int grow = g0 + sl;
        if (grow < BB * NQ) {
            const int bn = grow / MM, mm = grow % MM;
            const float mu = smu[sl], rs = srs[sl];
            float* obase = outp + (size_t)bn * 128 * MM + mm;
            for (int it = 0; it < 32; ++it) {
                int dd = it * 4 + du;
                obase[(size_t)dd * MM] = (zt[sl * 132 + dd] - mu) * rs * gam[dd] + bet[dd];
            }
        }
    }
}

extern "C" void kernel_launch(void* const* d_in, const int* in_sizes, int n_in,
                              void* d_out, int out_size, void* d_ws, size_t ws_size,
                              hipStream_t stream) {
    const float* q      = (const float*)d_in[0];
    const float* k      = (const float*)d_in[1];
    const float* v      = (const float*)d_in[2];
    const float* skip   = (const float*)d_in[3];
    const float* ln_q_g = (const float*)d_in[4];
    const float* ln_q_b = (const float*)d_in[5];
    const float* wq     = (const float*)d_in[6];
    const float* bq     = (const float*)d_in[7];
    const float* ln_k_g = (const float*)d_in[8];
    const float* ln_k_b = (const float*)d_in[9];
    const float* wk     = (const float*)d_in[10];
    const float* bk     = (const float*)d_in[11];
    const float* ln_v_g = (const float*)d_in[12];
    const float* ln_v_b = (const float*)d_in[13];
    const float* wv     = (const float*)d_in[14];
    const float* bv     = (const float*)d_in[15];
    const float* proj_w = (const float*)d_in[16];
    const float* proj_b = (const float*)d_in[17];
    const float* pre_g  = (const float*)d_in[18];
    const float* pre_b  = (const float*)d_in[19];
    const float* mlp_w1 = (const float*)d_in[20];
    const float* mlp_b1 = (const float*)d_in[21];
    const float* mlp_w2 = (const float*)d_in[22];
    const float* mlp_b2 = (const float*)d_in[23];
    const float* post_g = (const float*)d_in[24];
    const float* post_b = (const float*)d_in[25];

    float* ws   = (float*)d_ws;
    float* outp = (float*)d_out;

    float* qh   = ws + OFF_QH;
    float* kh   = ws + OFF_KH;
    float* vh   = ws + OFF_VH;
    float* pacc = ws + OFF_PACC;
    float* pm   = ws + OFF_PM;
    float* pl   = ws + OFF_PL;
    float* a    = ws + OFF_A;
    float* z0   = ws + OFF_Z0;    // aliases qh (safe: qh dead after attn_partial)
    float* zn   = ws + OFF_ZN;    // aliases kh
    float* hmid = ws + OFF_HMID;  // aliases vh

    k_lnproj<<<235, 128, 0, stream>>>(q, MM, BB * NQ, ln_q_g, ln_q_b, wq, bq, qh);
    k_lnproj<<<630, 128, 0, stream>>>(k, HWSZ, BB * NK, ln_k_g, ln_k_b, wk, bk, kh);
    k_lnproj<<<630, 128, 0, stream>>>(v, HWSZ, BB * NK, ln_v_g, ln_v_b, wv, bv, vh);
    k_attn_partial<<<BB * HEADS * NQT * KC, 64, 0, stream>>>(qh, kh, vh, pacc, pm, pl);
    k_attn_combine<<<3750, 256, 0, stream>>>(pacc, pm, pl, a);
    k_gemm_a<<<235, 128, 0, stream>>>(a, proj_w, proj_b, z0);
    k_skip_ln<<<235, 128, 0, stream>>>(z0, skip, pre_g, pre_b, zn);
    k_mlp1<<<235, 256, 0, stream>>>(zn, mlp_w1, mlp_b1, hmid);
    k_mlp2<<<235, 128, 0, stream>>>(hmid, zn, mlp_w2, mlp_b2, post_g, post_b, outp);
}

// Round 2
// 455.421 us; speedup vs baseline: 3.1612x; 3.1612x over previous
//
#include <hip/hip_runtime.h>
#include <hip/hip_bf16.h>
#include <math.h>

typedef __attribute__((ext_vector_type(8))) short bf16x8;
typedef __attribute__((ext_vector_type(4))) float f32x4;
typedef unsigned short u16;

#define BB 2
#define NN 6
#define MM 625
#define HWSZ 1680
#define NQ 3750
#define NK 10080
#define HEADS 4
#define EPSV 1e-5f
#define KC 3
#define KCHUNK 3360
#define NQT 59
#define SCALE 0.17677669529663687f

// ---- workspace offsets (floats) ----
#define OFF_QH   0          // bf16 960000  -> 480000 fl
#define OFF_KH   480000     // bf16 2580480 -> 1290240 fl
#define OFF_VH   1770240
#define OFF_PACC 3060480    // 2*4*3*3750*32 = 2880000 fl
#define OFF_PL   5940480    // 90000 fl
#define OFF_A    6030480    // 960000 fl
#define OFF_Z0   6990480
#define OFF_ZN   7950480
#define OFF_HMID 8910480    // 1920000 fl -> total 10830480

__device__ inline u16 f2bf(float f) {
    __hip_bfloat16 h = __float2bfloat16(f);
    return *reinterpret_cast<u16*>(&h);
}

// LN (over 128 channels, channel-strided input) + 128x128 projection + bias -> bf16 out.
__global__ void __launch_bounds__(128) k_lnproj(const float* __restrict__ x, int S, int rows,
        const float* __restrict__ gam, const float* __restrict__ bet,
        const float* __restrict__ Wt, const float* __restrict__ bias,
        u16* __restrict__ outp) {
    __shared__ float xs[32][132];
    __shared__ float smu[32], srs[32];
    const int t = threadIdx.x;
    const int g0 = blockIdx.x * 32;
    {
        const int sl = t & 31, du = t >> 5;
        const int grow = g0 + sl;
        const bool vload = grow < rows;
        const int bn = grow / S, ss = grow % S;
        const float* xbase = x + (size_t)bn * 128 * S + ss;
        for (int it = 0; it < 32; ++it) {
            int dd = it * 4 + du;
            xs[sl][dd] = vload ? xbase[(size_t)dd * S] : 0.f;
        }
    }
    __syncthreads();
    {
        const int r = t >> 2, p = t & 3;
        float sum = 0.f, sq = 0.f;
        for (int j = 0; j < 32; ++j) {
            float v = xs[r][p + 4 * j];
            sum += v; sq += v * v;
        }
        sum += __shfl_xor(sum, 1); sq += __shfl_xor(sq, 1);
        sum += __shfl_xor(sum, 2); sq += __shfl_xor(sq, 2);
        if (p == 0) {
            float mu = sum * (1.f / 128.f);
            float var = sq * (1.f / 128.f) - mu * mu;
            smu[r] = mu;
            srs[r] = rsqrtf(var + EPSV);
        }
    }
    __syncthreads();
    {
        const float gv = gam[t], bv = bet[t];
        for (int rr = 0; rr < 32; ++rr)
            xs[rr][t] = (xs[rr][t] - smu[rr]) * srs[rr] * gv + bv;
    }
    __syncthreads();
    float acc[32];
    #pragma unroll
    for (int rr = 0; rr < 32; ++rr) acc[rr] = 0.f;
    for (int d4 = 0; d4 < 32; ++d4) {
        const float w0 = Wt[(d4 * 4 + 0) * 128 + t];
        const float w1 = Wt[(d4 * 4 + 1) * 128 + t];
        const float w2 = Wt[(d4 * 4 + 2) * 128 + t];
        const float w3 = Wt[(d4 * 4 + 3) * 128 + t];
        #pragma unroll
        for (int rr = 0; rr < 32; ++rr) {
            float4 xv = *(const float4*)&xs[rr][d4 * 4];
            acc[rr] += xv.x * w0 + xv.y * w1 + xv.z * w2 + xv.w * w3;
        }
    }
    const float bb = bias[t];
    for (int rr = 0; rr < 32; ++rr) {
        int grow = g0 + rr;
        if (grow < rows) outp[(size_t)grow * 128 + t] = f2bf(acc[rr] + bb);
    }
}

// MFMA flash attention partial (fixed-max softmax).
// 4 waves/block, wave owns 16 queries; KBLK=32 keys/iter; split-K KC chunks.
__global__ void __launch_bounds__(256) k_attn_mfma(
        const u16* __restrict__ qh, const u16* __restrict__ kh, const u16* __restrict__ vh,
        float* __restrict__ pacc, float* __restrict__ pl) {
    __shared__ u16 Vs[32 * 40];       // V^T tile: [dh 32][keys 32 pad 40]
    __shared__ u16 Pw[4][16 * 40];    // per-wave P tile: [q 16][keys 32 pad 40]
    const int t = threadIdx.x;
    const int lane = t & 63, wid = t >> 6;
    const int g = lane >> 4, c = lane & 15;
    int bid = blockIdx.x;
    const int kc = bid % KC; bid /= KC;
    const int qt = bid % NQT; bid /= NQT;
    const int h = bid % HEADS;
    const int b = bid / HEADS;

    const int q0 = qt * 64 + wid * 16;
    int qa_row = q0 + c; if (qa_row > NQ - 1) qa_row = NQ - 1;
    const bf16x8 qa = *(const bf16x8*)(qh + ((size_t)b * NQ + qa_row) * 128 + h * 32 + g * 8);

    const u16* kbase = kh + (size_t)b * NK * 128 + h * 32;
    const u16* vbase = vh + (size_t)b * NK * 128 + h * 32;
    const int kstart = kc * KCHUNK, kend = kstart + KCHUNK;

    const int vkey = t >> 3, vdh = (t & 7) * 4;   // V staging: thread loads 4 dh of one key

    f32x4 acc0 = {0.f, 0.f, 0.f, 0.f}, acc1 = {0.f, 0.f, 0.f, 0.f};
    const f32x4 zero = {0.f, 0.f, 0.f, 0.f};
    float lsum[4] = {0.f, 0.f, 0.f, 0.f};

    // prefetch tile 0
    bf16x8 kb0 = *(const bf16x8*)(kbase + (size_t)(kstart + c) * 128 + g * 8);
    bf16x8 kb1 = *(const bf16x8*)(kbase + (size_t)(kstart + 16 + c) * 128 + g * 8);
    ushort4 vld = *(const ushort4*)(vbase + (size_t)(kstart + vkey) * 128 + vdh);

    for (int k0 = kstart; k0 < kend; k0 += 32) {
        __syncthreads();                       // Vs free (prev consumers done)
        Vs[(vdh + 0) * 40 + vkey] = vld.x;     // transpose during staging
        Vs[(vdh + 1) * 40 + vkey] = vld.y;
        Vs[(vdh + 2) * 40 + vkey] = vld.z;
        Vs[(vdh + 3) * 40 + vkey] = vld.w;
        // prefetch next tile (dummy reload of kstart on last iter)
        int kn = k0 + 32; if (kn >= kend) kn = kstart;
        ushort4 vld_n = *(const ushort4*)(vbase + (size_t)(kn + vkey) * 128 + vdh);
        bf16x8 kb0n = *(const bf16x8*)(kbase + (size_t)(kn + c) * 128 + g * 8);
        bf16x8 kb1n = *(const bf16x8*)(kbase + (size_t)(kn + 16 + c) * 128 + g * 8);

        f32x4 s0 = __builtin_amdgcn_mfma_f32_16x16x32_bf16(qa, kb0, zero, 0, 0, 0);
        f32x4 s1 = __builtin_amdgcn_mfma_f32_16x16x32_bf16(qa, kb1, zero, 0, 0, 0);

        u16* prow = &Pw[wid][0];
        #pragma unroll
        for (int r = 0; r < 4; ++r) {
            float p0 = __expf(s0[r] * SCALE);
            float p1 = __expf(s1[r] * SCALE);
            lsum[r] += p0 + p1;
            int q = g * 4 + r;
            prow[q * 40 + c]      = f2bf(p0);
            prow[q * 40 + c + 16] = f2bf(p1);
        }
        bf16x8 pa = *(const bf16x8*)&Pw[wid][c * 40 + g * 8];
        __syncthreads();                       // Vs staged
        bf16x8 vb0 = *(const bf16x8*)&Vs[c * 40 + g * 8];
        bf16x8 vb1 = *(const bf16x8*)&Vs[(c + 16) * 40 + g * 8];
        acc0 = __builtin_amdgcn_mfma_f32_16x16x32_bf16(pa, vb0, acc0, 0, 0, 0);
        acc1 = __builtin_amdgcn_mfma_f32_16x16x32_bf16(pa, vb1, acc1, 0, 0, 0);
        kb0 = kb0n; kb1 = kb1n; vld = vld_n;
    }

    #pragma unroll
    for (int r = 0; r < 4; ++r) {
        lsum[r] += __shfl_xor(lsum[r], 1);
        lsum[r] += __shfl_xor(lsum[r], 2);
        lsum[r] += __shfl_xor(lsum[r], 4);
        lsum[r] += __shfl_xor(lsum[r], 8);
    }
    const int pi = (b * HEADS + h) * KC + kc;
    #pragma unroll
    for (int r = 0; r < 4; ++r) {
        int qq = q0 + g * 4 + r;
        if (qq < NQ) {
            float* pr = pacc + ((size_t)pi * NQ + qq) * 32;
            pr[c] = acc0[r];
            pr[c + 16] = acc1[r];
            if (c == 0) pl[(size_t)pi * NQ + qq] = lsum[r];
        }
    }
}

__global__ void __launch_bounds__(256) k_attn_combine(const float* __restrict__ pacc,
        const float* __restrict__ pl, float* __restrict__ a) {
    const int idx = blockIdx.x * 256 + threadIdx.x;   // B*H*NQ*32, exact
    const int j = idx & 31;
    const int qq = (idx >> 5) % NQ;
    const int bh = idx / (32 * NQ);
    const int b = bh / HEADS, h = bh % HEADS;
    float L = 0.f, val = 0.f;
    #pragma unroll
    for (int kc = 0; kc < KC; ++kc) {
        size_t pi = (size_t)(bh * KC + kc) * NQ + qq;
        L += pl[pi];
        val += pacc[pi * 32 + j];
    }
    a[((size_t)b * NQ + qq) * 128 + h * 32 + j] = val / L;
}

// out-projection: z0 = a @ proj_w + proj_b
__global__ void __launch_bounds__(128) k_gemm_a(const float* __restrict__ a,
        const float* __restrict__ Wt, const float* __restrict__ bias,
        float* __restrict__ z0) {
    __shared__ float xs[32][132];
    const int t = threadIdx.x;
    const int g0 = blockIdx.x * 32;
    for (int rr = 0; rr < 32; ++rr) {
        int grow = g0 + rr;
        xs[rr][t] = (grow < BB * NQ) ? a[(size_t)grow * 128 + t] : 0.f;
    }
    __syncthreads();
    float acc[32];
    #pragma unroll
    for (int rr = 0; rr < 32; ++rr) acc[rr] = 0.f;
    for (int d4 = 0; d4 < 32; ++d4) {
        const float w0 = Wt[(d4 * 4 + 0) * 128 + t];
        const float w1 = Wt[(d4 * 4 + 1) * 128 + t];
        const float w2 = Wt[(d4 * 4 + 2) * 128 + t];
        const float w3 = Wt[(d4 * 4 + 3) * 128 + t];
        #pragma unroll
        for (int rr = 0; rr < 32; ++rr) {
            float4 xv = *(const float4*)&xs[rr][d4 * 4];
            acc[rr] += xv.x * w0 + xv.y * w1 + xv.z * w2 + xv.w * w3;
        }
    }
    const float bb = bias[t];
    for (int rr = 0; rr < 32; ++rr) {
        int grow = g0 + rr;
        if (grow < BB * NQ) z0[(size_t)grow * 128 + t] = acc[rr] + bb;
    }
}

// z0 + skip (channel-strided) -> pre-LN -> zn
__global__ void __launch_bounds__(128) k_skip_ln(const float* __restrict__ z0,
        const float* __restrict__ skip,
        const float* __restrict__ gam, const float* __restrict__ bet,
        float* __restrict__ zn) {
    __shared__ float xs[32][132];
    __shared__ float smu[32], srs[32];
    const int t = threadIdx.x;
    const int g0 = blockIdx.x * 32;
    for (int rr = 0; rr < 32; ++rr) {
        int grow = g0 + rr;
        xs[rr][t] = (grow < BB * NQ) ? z0[(size_t)grow * 128 + t] : 0.f;
    }
    __syncthreads();
    {
        const int sl = t & 31, du = t >> 5;
        const int grow = g0 + sl;
        if (grow < BB * NQ) {
            const int bn = grow / MM, mm = grow % MM;
            const float* sbase = skip + (size_t)bn * 128 * MM + mm;
            for (int it = 0; it < 32; ++it) {
                int dd = it * 4 + du;
                xs[sl][dd] += sbase[(size_t)dd * MM];
            }
        }
    }
    __syncthreads();
    {
        const int r = t >> 2, p = t & 3;
        float sum = 0.f, sq = 0.f;
        for (int j = 0; j < 32; ++j) {
            float v = xs[r][p + 4 * j];
            sum += v; sq += v * v;
        }
        sum += __shfl_xor(sum, 1); sq += __shfl_xor(sq, 1);
        sum += __shfl_xor(sum, 2); sq += __shfl_xor(sq, 2);
        if (p == 0) {
            float mu = sum * (1.f / 128.f);
            float var = sq * (1.f / 128.f) - mu * mu;
            smu[r] = mu;
            srs[r] = rsqrtf(var + EPSV);
        }
    }
    __syncthreads();
    const float gv = gam[t], bv = bet[t];
    for (int rr = 0; rr < 32; ++rr) {
        int grow = g0 + rr;
        if (grow < BB * NQ)
            zn[(size_t)grow * 128 + t] = (xs[rr][t] - smu[rr]) * srs[rr] * gv + bv;
    }
}

// hmid = gelu(zn @ w1 + b1), 128->256
__global__ void __launch_bounds__(256) k_mlp1(const float* __restrict__ zn,
        const float* __restrict__ W1, const float* __restrict__ b1,
        float* __restrict__ hmid) {
    __shared__ float xs[32][132];
    const int t = threadIdx.x;
    const int g0 = blockIdx.x * 32;
    for (int it = 0; it < 16; ++it) {
        int rr = it * 2 + (t >> 7);
        int cc = t & 127;
        int grow = g0 + rr;
        xs[rr][cc] = (grow < BB * NQ) ? zn[(size_t)grow * 128 + cc] : 0.f;
    }
    __syncthreads();
    float acc[32];
    #pragma unroll
    for (int rr = 0; rr < 32; ++rr) acc[rr] = 0.f;
    for (int d4 = 0; d4 < 32; ++d4) {
        const float w0 = W1[(d4 * 4 + 0) * 256 + t];
        const float w1 = W1[(d4 * 4 + 1) * 256 + t];
        const float w2 = W1[(d4 * 4 + 2) * 256 + t];
        const float w3 = W1[(d4 * 4 + 3) * 256 + t];
        #pragma unroll
        for (int rr = 0; rr < 32; ++rr) {
            float4 xv = *(const float4*)&xs[rr][d4 * 4];
            acc[rr] += xv.x * w0 + xv.y * w1 + xv.z * w2 + xv.w * w3;
        }
    }
    const float bb = b1[t];
    for (int rr = 0; rr < 32; ++rr) {
        int grow = g0 + rr;
        if (grow < BB * NQ) {
            float x = acc[rr] + bb;
            hmid[(size_t)grow * 256 + t] = 0.5f * x * (1.f + erff(x * 0.70710678118654752f));
        }
    }
}

// z2 = zn + hmid @ w2 + b2 ; post-LN ; transposed write to out (B,N,128,M)
__global__ void __launch_bounds__(128) k_mlp2(const float* __restrict__ hmid,
        const float* __restrict__ zn,
        const float* __restrict__ W2, const float* __restrict__ b2,
        const float* __restrict__ gam, const float* __restrict__ bet,
        float* __restrict__ outp) {
    __shared__ float hs[32][260];
    __shared__ float smu[32], srs[32];
    const int t = threadIdx.x;
    const int g0 = blockIdx.x * 32;
    for (int it = 0; it < 64; ++it) {
        int rr = it >> 1;
        int cc = (it & 1) * 128 + t;
        int grow = g0 + rr;
        hs[rr][cc] = (grow < BB * NQ) ? hmid[(size_t)grow * 256 + cc] : 0.f;
    }
    __syncthreads();
    float acc[32];
    #pragma unroll
    for (int rr = 0; rr < 32; ++rr) acc[rr] = 0.f;
    for (int d4 = 0; d4 < 64; ++d4) {
        const float w0 = W2[(d4 * 4 + 0) * 128 + t];
        const float w1 = W2[(d4 * 4 + 1) * 128 + t];
        const float w2 = W2[(d4 * 4 + 2) * 128 + t];
        const float w3 = W2[(d4 * 4 + 3) * 128 + t];
        #pragma unroll
        for (int rr = 0; rr < 32; ++rr) {
            float4 hv = *(const float4*)&hs[rr][d4 * 4];
            acc[rr] += hv.x * w0 + hv.y * w1 + hv.z * w2 + hv.w * w3;
        }
    }
    __syncthreads();
    float* zt = &hs[0][0];
    const float bb = b2[t];
    for (int rr = 0; rr < 32; ++rr) {
        int grow = g0 + rr;
        float zv = (grow < BB * NQ) ? zn[(size_t)grow * 128 + t] : 0.f;
        zt[rr * 132 + t] = zv + acc[rr] + bb;
    }
    __syncthreads();
    {
        const int r = t >> 2, p = t & 3;
        float sum = 0.f, sq = 0.f;
        for (int j = 0; j < 32; ++j) {
            float v = zt[r * 132 + p + 4 * j];
            sum += v; sq += v * v;
        }
        sum += __shfl_xor(sum, 1); sq += __shfl_xor(sq, 1);
        sum += __shfl_xor(sum, 2); sq += __shfl_xor(sq, 2);
        if (p == 0) {
            float mu = sum * (1.f / 128.f);
            float var = sq * (1.f / 128.f) - mu * mu;
            smu[r] = mu;
            srs[r] = rsqrtf(var + EPSV);
        }
    }
    __syncthreads();
    {
        const int sl = t & 31, du = t >> 5;
        const int grow = g0 + sl;
        if (grow < BB * NQ) {
            const int bn = grow / MM, mm = grow % MM;
            const float mu = smu[sl], rs = srs[sl];
            float* obase = outp + (size_t)bn * 128 * MM + mm;
            for (int it = 0; it < 32; ++it) {
                int dd = it * 4 + du;
                obase[(size_t)dd * MM] = (zt[sl * 132 + dd] - mu) * rs * gam[dd] + bet[dd];
            }
        }
    }
}

extern "C" void kernel_launch(void* const* d_in, const int* in_sizes, int n_in,
                              void* d_out, int out_size, void* d_ws, size_t ws_size,
                              hipStream_t stream) {
    const float* q      = (const float*)d_in[0];
    const float* k      = (const float*)d_in[1];
    const float* v      = (const float*)d_in[2];
    const float* skip   = (const float*)d_in[3];
    const float* ln_q_g = (const float*)d_in[4];
    const float* ln_q_b = (const float*)d_in[5];
    const float* wq     = (const float*)d_in[6];
    const float* bq     = (const float*)d_in[7];
    const float* ln_k_g = (const float*)d_in[8];
    const float* ln_k_b = (const float*)d_in[9];
    const float* wk     = (const float*)d_in[10];
    const float* bk     = (const float*)d_in[11];
    const float* ln_v_g = (const float*)d_in[12];
    const float* ln_v_b = (const float*)d_in[13];
    const float* wv     = (const float*)d_in[14];
    const float* bv     = (const float*)d_in[15];
    const float* proj_w = (const float*)d_in[16];
    const float* proj_b = (const float*)d_in[17];
    const float* pre_g  = (const float*)d_in[18];
    const float* pre_b  = (const float*)d_in[19];
    const float* mlp_w1 = (const float*)d_in[20];
    const float* mlp_b1 = (const float*)d_in[21];
    const float* mlp_w2 = (const float*)d_in[22];
    const float* mlp_b2 = (const float*)d_in[23];
    const float* post_g = (const float*)d_in[24];
    const float* post_b = (const float*)d_in[25];

    float* ws   = (float*)d_ws;
    float* outp = (float*)d_out;

    u16* qh   = (u16*)(ws + OFF_QH);
    u16* kh   = (u16*)(ws + OFF_KH);
    u16* vh   = (u16*)(ws + OFF_VH);
    float* pacc = ws + OFF_PACC;
    float* pl   = ws + OFF_PL;
    float* a    = ws + OFF_A;
    float* z0   = ws + OFF_Z0;
    float* zn   = ws + OFF_ZN;
    float* hmid = ws + OFF_HMID;

    k_lnproj<<<235, 128, 0, stream>>>(q, MM, BB * NQ, ln_q_g, ln_q_b, wq, bq, qh);
    k_lnproj<<<630, 128, 0, stream>>>(k, HWSZ, BB * NK, ln_k_g, ln_k_b, wk, bk, kh);
    k_lnproj<<<630, 128, 0, stream>>>(v, HWSZ, BB * NK, ln_v_g, ln_v_b, wv, bv, vh);
    k_attn_mfma<<<BB * HEADS * NQT * KC, 256, 0, stream>>>(qh, kh, vh, pacc, pl);
    k_attn_combine<<<3750, 256, 0, stream>>>(pacc, pl, a);
    k_gemm_a<<<235, 128, 0, stream>>>(a, proj_w, proj_b, z0);
    k_skip_ln<<<235, 128, 0, stream>>>(z0, skip, pre_g, pre_b, zn);
    k_mlp1<<<235, 256, 0, stream>>>(zn, mlp_w1, mlp_b1, hmid);
    k_mlp2<<<235, 128, 0, stream>>>(hmid, zn, mlp_w2, mlp_b2, post_g, post_b, outp);
}

// Round 3
// 408.165 us; speedup vs baseline: 3.5272x; 1.1158x over previous
//
#include <hip/hip_runtime.h>
#include <hip/hip_bf16.h>
#include <math.h>

typedef __attribute__((ext_vector_type(8))) short bf16x8;
typedef __attribute__((ext_vector_type(4))) float f32x4;
typedef __attribute__((ext_vector_type(16))) float f32x16;
typedef unsigned short u16;
typedef unsigned int u32;

#define BB 2
#define NN 6
#define MM 625
#define HWSZ 1680
#define NQ 3750
#define NK 10080
#define HEADS 4
#define EPSV 1e-5f
#define KC 3
#define KCHUNK 3360
#define ITERS 105            // KCHUNK/32
#define NQT128 30            // ceil(3750/128)
#define QPRESCALE 0.25503489f   // (1/sqrt(32)) * log2(e)

// ---- workspace offsets (floats) ----
#define OFF_QH   0          // bf16 960000  -> 480000 fl
#define OFF_KH   480000     // bf16 2580480 -> 1290240 fl
#define OFF_VH   1770240
#define OFF_PACC 3060480    // 2*4*3*3750*32 = 2880000 fl
#define OFF_PL   5940480    // 90000 fl
#define OFF_A    6030480    // 960000 fl
#define OFF_Z0   6990480
#define OFF_ZN   7950480
#define OFF_HMID 8910480    // 1920000 fl -> total 10830480

__device__ inline u16 f2bf(float f) {
    __hip_bfloat16 h = __float2bfloat16(f);
    return *reinterpret_cast<u16*>(&h);
}

__device__ inline bf16x8 mk_frag(u32 a, u32 b, u32 c, u32 d) {
    union { u32 u[4]; bf16x8 v; } x;
    x.u[0] = a; x.u[1] = b; x.u[2] = c; x.u[3] = d;
    return x.v;
}

// LN (over 128 channels, channel-strided input) + 128x128 projection + bias -> bf16 out.
// oscale: extra output scale (folds attention's softmax scale*log2e into Q).
__global__ void __launch_bounds__(128) k_lnproj(const float* __restrict__ x, int S, int rows,
        const float* __restrict__ gam, const float* __restrict__ bet,
        const float* __restrict__ Wt, const float* __restrict__ bias,
        float oscale, u16* __restrict__ outp) {
    __shared__ float xs[32][132];
    __shared__ float smu[32], srs[32];
    const int t = threadIdx.x;
    const int g0 = blockIdx.x * 32;
    {
        const int sl = t & 31, du = t >> 5;
        const int grow = g0 + sl;
        const bool vload = grow < rows;
        const int bn = grow / S, ss = grow % S;
        const float* xbase = x + (size_t)bn * 128 * S + ss;
        for (int it = 0; it < 32; ++it) {
            int dd = it * 4 + du;
            xs[sl][dd] = vload ? xbase[(size_t)dd * S] : 0.f;
        }
    }
    __syncthreads();
    {
        const int r = t >> 2, p = t & 3;
        float sum = 0.f, sq = 0.f;
        for (int j = 0; j < 32; ++j) {
            float v = xs[r][p + 4 * j];
            sum += v; sq += v * v;
        }
        sum += __shfl_xor(sum, 1); sq += __shfl_xor(sq, 1);
        sum += __shfl_xor(sum, 2); sq += __shfl_xor(sq, 2);
        if (p == 0) {
            float mu = sum * (1.f / 128.f);
            float var = sq * (1.f / 128.f) - mu * mu;
            smu[r] = mu;
            srs[r] = rsqrtf(var + EPSV);
        }
    }
    __syncthreads();
    {
        const float gv = gam[t], bv = bet[t];
        for (int rr = 0; rr < 32; ++rr)
            xs[rr][t] = (xs[rr][t] - smu[rr]) * srs[rr] * gv + bv;
    }
    __syncthreads();
    float acc[32];
    #pragma unroll
    for (int rr = 0; rr < 32; ++rr) acc[rr] = 0.f;
    for (int d4 = 0; d4 < 32; ++d4) {
        const float w0 = Wt[(d4 * 4 + 0) * 128 + t];
        const float w1 = Wt[(d4 * 4 + 1) * 128 + t];
        const float w2 = Wt[(d4 * 4 + 2) * 128 + t];
        const float w3 = Wt[(d4 * 4 + 3) * 128 + t];
        #pragma unroll
        for (int rr = 0; rr < 32; ++rr) {
            float4 xv = *(const float4*)&xs[rr][d4 * 4];
            acc[rr] += xv.x * w0 + xv.y * w1 + xv.z * w2 + xv.w * w3;
        }
    }
    const float bb = bias[t];
    for (int rr = 0; rr < 32; ++rr) {
        int grow = g0 + rr;
        if (grow < rows) outp[(size_t)grow * 128 + t] = f2bf((acc[rr] + bb) * oscale);
    }
}

// MFMA flash attention partial, 32x32 swapped-QK^T, in-register softmax.
// 4 waves/block, wave owns 32 queries; 32 keys/iter; split-K KC chunks.
__global__ void __launch_bounds__(256) k_attn_mfma(
        const u16* __restrict__ qh, const u16* __restrict__ kh, const u16* __restrict__ vh,
        float* __restrict__ pacc, float* __restrict__ pl) {
    __shared__ u16 Vs[32 * 40];       // V^T tile: [dh 32][keys 32, stride 40]
    const int t = threadIdx.x;
    const int lane = t & 63, wid = t >> 6;
    const int rl = lane & 31, hi = lane >> 5;
    int bid = blockIdx.x;
    const int kc = bid % KC; bid /= KC;
    const int qt = bid % NQT128; bid /= NQT128;
    const int h = bid % HEADS;
    const int b = bid / HEADS;
    const int q0w = qt * 128 + wid * 32;

    int qrow = q0w + rl; if (qrow > NQ - 1) qrow = NQ - 1;
    const u16* qp = qh + ((size_t)b * NQ + qrow) * 128 + h * 32;
    const bf16x8 qf0 = *(const bf16x8*)(qp + hi * 8);        // B-frag, dh 0..15
    const bf16x8 qf1 = *(const bf16x8*)(qp + 16 + hi * 8);   // B-frag, dh 16..31

    const u16* kbase = kh + (size_t)b * NK * 128 + h * 32;
    const u16* vbase = vh + (size_t)b * NK * 128 + h * 32;
    const int kstart = kc * KCHUNK;

    const int vkey = t & 31, vdhg = t >> 5;   // staging: thread owns (key, 4-dh group)

    f32x16 acc;
    #pragma unroll
    for (int i = 0; i < 16; ++i) acc[i] = 0.f;
    f32x16 zero16;
    #pragma unroll
    for (int i = 0; i < 16; ++i) zero16[i] = 0.f;
    float lsum = 0.f;

    // prefetch tile 0
    bf16x8 kf0 = *(const bf16x8*)(kbase + (size_t)(kstart + rl) * 128 + hi * 8);
    bf16x8 kf1 = *(const bf16x8*)(kbase + (size_t)(kstart + rl) * 128 + 16 + hi * 8);
    ushort4 vld = *(const ushort4*)(vbase + (size_t)(kstart + vkey) * 128 + vdhg * 4);

    for (int ii = 0; ii < ITERS; ++ii) {
        __syncthreads();                       // prev Vs consumers done
        {   // stage V^T (write banks span all 32: 2-way free)
            u16* vs = &Vs[vdhg * 4 * 40 + vkey];
            vs[0]      = vld.x;
            vs[40]     = vld.y;
            vs[80]     = vld.z;
            vs[120]    = vld.w;
        }
        // prefetch next tile (dummy reload of kstart on last iter)
        int knext = (ii + 1 < ITERS) ? kstart + (ii + 1) * 32 : kstart;
        ushort4 vnx = *(const ushort4*)(vbase + (size_t)(knext + vkey) * 128 + vdhg * 4);
        bf16x8 kn0 = *(const bf16x8*)(kbase + (size_t)(knext + rl) * 128 + hi * 8);
        bf16x8 kn1 = *(const bf16x8*)(kbase + (size_t)(knext + rl) * 128 + 16 + hi * 8);

        // S^T = K · Q^T : lane holds q=rl, keys (reg&3)+8*(reg>>2)+4*hi
        f32x16 s = __builtin_amdgcn_mfma_f32_32x32x16_bf16(kf0, qf0, zero16, 0, 0, 0);
        s = __builtin_amdgcn_mfma_f32_32x32x16_bf16(kf1, qf1, s, 0, 0, 0);

        // softmax numerators (fixed max=0; Q pre-scaled by SCALE*log2e)
        u32 dw0, dw1, dw2, dw3, dw4, dw5, dw6, dw7;
        {
            float pa, pb;
            pa = exp2f(s[0]);  pb = exp2f(s[1]);  lsum += pa + pb;
            asm("v_cvt_pk_bf16_f32 %0, %1, %2" : "=v"(dw0) : "v"(pa), "v"(pb));
            pa = exp2f(s[2]);  pb = exp2f(s[3]);  lsum += pa + pb;
            asm("v_cvt_pk_bf16_f32 %0, %1, %2" : "=v"(dw1) : "v"(pa), "v"(pb));
            pa = exp2f(s[4]);  pb = exp2f(s[5]);  lsum += pa + pb;
            asm("v_cvt_pk_bf16_f32 %0, %1, %2" : "=v"(dw2) : "v"(pa), "v"(pb));
            pa = exp2f(s[6]);  pb = exp2f(s[7]);  lsum += pa + pb;
            asm("v_cvt_pk_bf16_f32 %0, %1, %2" : "=v"(dw3) : "v"(pa), "v"(pb));
            pa = exp2f(s[8]);  pb = exp2f(s[9]);  lsum += pa + pb;
            asm("v_cvt_pk_bf16_f32 %0, %1, %2" : "=v"(dw4) : "v"(pa), "v"(pb));
            pa = exp2f(s[10]); pb = exp2f(s[11]); lsum += pa + pb;
            asm("v_cvt_pk_bf16_f32 %0, %1, %2" : "=v"(dw5) : "v"(pa), "v"(pb));
            pa = exp2f(s[12]); pb = exp2f(s[13]); lsum += pa + pb;
            asm("v_cvt_pk_bf16_f32 %0, %1, %2" : "=v"(dw6) : "v"(pa), "v"(pb));
            pa = exp2f(s[14]); pb = exp2f(s[15]); lsum += pa + pb;
            asm("v_cvt_pk_bf16_f32 %0, %1, %2" : "=v"(dw7) : "v"(pa), "v"(pb));
        }
        // cross-half exchange: each swap yields BOTH PV A-frag words (T12)
        asm("v_permlane32_swap_b32 %0, %1" : "+v"(dw0), "+v"(dw2));
        asm("v_permlane32_swap_b32 %0, %1" : "+v"(dw1), "+v"(dw3));
        asm("v_permlane32_swap_b32 %0, %1" : "+v"(dw4), "+v"(dw6));
        asm("v_permlane32_swap_b32 %0, %1" : "+v"(dw5), "+v"(dw7));
        const bf16x8 pfrag0 = mk_frag(dw0, dw1, dw2, dw3);   // keys hi*8..+7
        const bf16x8 pfrag1 = mk_frag(dw4, dw5, dw6, dw7);   // keys 16+hi*8..+7

        __syncthreads();                       // Vs staged
        const bf16x8 vf0 = *(const bf16x8*)&Vs[rl * 40 + hi * 8];        // B-frag keys 0..15
        const bf16x8 vf1 = *(const bf16x8*)&Vs[rl * 40 + 16 + hi * 8];   // B-frag keys 16..31
        acc = __builtin_amdgcn_mfma_f32_32x32x16_bf16(pfrag0, vf0, acc, 0, 0, 0);
        acc = __builtin_amdgcn_mfma_f32_32x32x16_bf16(pfrag1, vf1, acc, 0, 0, 0);

        kf0 = kn0; kf1 = kn1; vld = vnx;
    }

    // denominators: partner holds the other 16 keys
    float ltot = lsum + __shfl_xor(lsum, 32);

    const int pi = (b * HEADS + h) * KC + kc;
    // acc layout: lane holds dh=rl for q_local=(reg&3)+8*(reg>>2)+4*hi
    #pragma unroll
    for (int reg = 0; reg < 16; ++reg) {
        int qloc = (reg & 3) + 8 * (reg >> 2) + 4 * hi;
        int qq = q0w + qloc;
        if (qq < NQ) pacc[((size_t)pi * NQ + qq) * 32 + rl] = acc[reg];
    }
    if (hi == 0) {
        int qq = q0w + rl;
        if (qq < NQ) pl[(size_t)pi * NQ + qq] = ltot;
    }
}

__global__ void __launch_bounds__(256) k_attn_combine(const float* __restrict__ pacc,
        const float* __restrict__ pl, float* __restrict__ a) {
    const int idx = blockIdx.x * 256 + threadIdx.x;   // B*H*NQ*32, exact
    const int j = idx & 31;
    const int qq = (idx >> 5) % NQ;
    const int bh = idx / (32 * NQ);
    const int b = bh / HEADS, h = bh % HEADS;
    float L = 0.f, val = 0.f;
    #pragma unroll
    for (int kc = 0; kc < KC; ++kc) {
        size_t pi = (size_t)(bh * KC + kc) * NQ + qq;
        L += pl[pi];
        val += pacc[pi * 32 + j];
    }
    a[((size_t)b * NQ + qq) * 128 + h * 32 + j] = val / L;
}

// out-projection: z0 = a @ proj_w + proj_b
__global__ void __launch_bounds__(128) k_gemm_a(const float* __restrict__ a,
        const float* __restrict__ Wt, const float* __restrict__ bias,
        float* __restrict__ z0) {
    __shared__ float xs[32][132];
    const int t = threadIdx.x;
    const int g0 = blockIdx.x * 32;
    for (int rr = 0; rr < 32; ++rr) {
        int grow = g0 + rr;
        xs[rr][t] = (grow < BB * NQ) ? a[(size_t)grow * 128 + t] : 0.f;
    }
    __syncthreads();
    float acc[32];
    #pragma unroll
    for (int rr = 0; rr < 32; ++rr) acc[rr] = 0.f;
    for (int d4 = 0; d4 < 32; ++d4) {
        const float w0 = Wt[(d4 * 4 + 0) * 128 + t];
        const float w1 = Wt[(d4 * 4 + 1) * 128 + t];
        const float w2 = Wt[(d4 * 4 + 2) * 128 + t];
        const float w3 = Wt[(d4 * 4 + 3) * 128 + t];
        #pragma unroll
        for (int rr = 0; rr < 32; ++rr) {
            float4 xv = *(const float4*)&xs[rr][d4 * 4];
            acc[rr] += xv.x * w0 + xv.y * w1 + xv.z * w2 + xv.w * w3;
        }
    }
    const float bb = bias[t];
    for (int rr = 0; rr < 32; ++rr) {
        int grow = g0 + rr;
        if (grow < BB * NQ) z0[(size_t)grow * 128 + t] = acc[rr] + bb;
    }
}

// z0 + skip (channel-strided) -> pre-LN -> zn
__global__ void __launch_bounds__(128) k_skip_ln(const float* __restrict__ z0,
        const float* __restrict__ skip,
        const float* __restrict__ gam, const float* __restrict__ bet,
        float* __restrict__ zn) {
    __shared__ float xs[32][132];
    __shared__ float smu[32], srs[32];
    const int t = threadIdx.x;
    const int g0 = blockIdx.x * 32;
    for (int rr = 0; rr < 32; ++rr) {
        int grow = g0 + rr;
        xs[rr][t] = (grow < BB * NQ) ? z0[(size_t)grow * 128 + t] : 0.f;
    }
    __syncthreads();
    {
        const int sl = t & 31, du = t >> 5;
        const int grow = g0 + sl;
        if (grow < BB * NQ) {
            const int bn = grow / MM, mm = grow % MM;
            const float* sbase = skip + (size_t)bn * 128 * MM + mm;
            for (int it = 0; it < 32; ++it) {
                int dd = it * 4 + du;
                xs[sl][dd] += sbase[(size_t)dd * MM];
            }
        }
    }
    __syncthreads();
    {
        const int r = t >> 2, p = t & 3;
        float sum = 0.f, sq = 0.f;
        for (int j = 0; j < 32; ++j) {
            float v = xs[r][p + 4 * j];
            sum += v; sq += v * v;
        }
        sum += __shfl_xor(sum, 1); sq += __shfl_xor(sq, 1);
        sum += __shfl_xor(sum, 2); sq += __shfl_xor(sq, 2);
        if (p == 0) {
            float mu = sum * (1.f / 128.f);
            float var = sq * (1.f / 128.f) - mu * mu;
            smu[r] = mu;
            srs[r] = rsqrtf(var + EPSV);
        }
    }
    __syncthreads();
    const float gv = gam[t], bv = bet[t];
    for (int rr = 0; rr < 32; ++rr) {
        int grow = g0 + rr;
        if (grow < BB * NQ)
            zn[(size_t)grow * 128 + t] = (xs[rr][t] - smu[rr]) * srs[rr] * gv + bv;
    }
}

// hmid = gelu(zn @ w1 + b1), 128->256
__global__ void __launch_bounds__(256) k_mlp1(const float* __restrict__ zn,
        const float* __restrict__ W1, const float* __restrict__ b1,
        float* __restrict__ hmid) {
    __shared__ float xs[32][132];
    const int t = threadIdx.x;
    const int g0 = blockIdx.x * 32;
    for (int it = 0; it < 16; ++it) {
        int rr = it * 2 + (t >> 7);
        int cc = t & 127;
        int grow = g0 + rr;
        xs[rr][cc] = (grow < BB * NQ) ? zn[(size_t)grow * 128 + cc] : 0.f;
    }
    __syncthreads();
    float acc[32];
    #pragma unroll
    for (int rr = 0; rr < 32; ++rr) acc[rr] = 0.f;
    for (int d4 = 0; d4 < 32; ++d4) {
        const float w0 = W1[(d4 * 4 + 0) * 256 + t];
        const float w1 = W1[(d4 * 4 + 1) * 256 + t];
        const float w2 = W1[(d4 * 4 + 2) * 256 + t];
        const float w3 = W1[(d4 * 4 + 3) * 256 + t];
        #pragma unroll
        for (int rr = 0; rr < 32; ++rr) {
            float4 xv = *(const float4*)&xs[rr][d4 * 4];
            acc[rr] += xv.x * w0 + xv.y * w1 + xv.z * w2 + xv.w * w3;
        }
    }
    const float bb = b1[t];
    for (int rr = 0; rr < 32; ++rr) {
        int grow = g0 + rr;
        if (grow < BB * NQ) {
            float x = acc[rr] + bb;
            hmid[(size_t)grow * 256 + t] = 0.5f * x * (1.f + erff(x * 0.70710678118654752f));
        }
    }
}

// z2 = zn + hmid @ w2 + b2 ; post-LN ; transposed write to out (B,N,128,M)
__global__ void __launch_bounds__(128) k_mlp2(const float* __restrict__ hmid,
        const float* __restrict__ zn,
        const float* __restrict__ W2, const float* __restrict__ b2,
        const float* __restrict__ gam, const float* __restrict__ bet,
        float* __restrict__ outp) {
    __shared__ float hs[32][260];
    __shared__ float smu[32], srs[32];
    const int t = threadIdx.x;
    const int g0 = blockIdx.x * 32;
    for (int it = 0; it < 64; ++it) {
        int rr = it >> 1;
        int cc = (it & 1) * 128 + t;
        int grow = g0 + rr;
        hs[rr][cc] = (grow < BB * NQ) ? hmid[(size_t)grow * 256 + cc] : 0.f;
    }
    __syncthreads();
    float acc[32];
    #pragma unroll
    for (int rr = 0; rr < 32; ++rr) acc[rr] = 0.f;
    for (int d4 = 0; d4 < 64; ++d4) {
        const float w0 = W2[(d4 * 4 + 0) * 128 + t];
        const float w1 = W2[(d4 * 4 + 1) * 128 + t];
        const float w2 = W2[(d4 * 4 + 2) * 128 + t];
        const float w3 = W2[(d4 * 4 + 3) * 128 + t];
        #pragma unroll
        for (int rr = 0; rr < 32; ++rr) {
            float4 hv = *(const float4*)&hs[rr][d4 * 4];
            acc[rr] += hv.x * w0 + hv.y * w1 + hv.z * w2 + hv.w * w3;
        }
    }
    __syncthreads();
    float* zt = &hs[0][0];
    const float bb = b2[t];
    for (int rr = 0; rr < 32; ++rr) {
        int grow = g0 + rr;
        float zv = (grow < BB * NQ) ? zn[(size_t)grow * 128 + t] : 0.f;
        zt[rr * 132 + t] = zv + acc[rr] + bb;
    }
    __syncthreads();
    {
        const int r = t >> 2, p = t & 3;
        float sum = 0.f, sq = 0.f;
        for (int j = 0; j < 32; ++j) {
            float v = zt[r * 132 + p + 4 * j];
            sum += v; sq += v * v;
        }
        sum += __shfl_xor(sum, 1); sq += __shfl_xor(sq, 1);
        sum += __shfl_xor(sum, 2); sq += __shfl_xor(sq, 2);
        if (p == 0) {
            float mu = sum * (1.f / 128.f);
            float var = sq * (1.f / 128.f) - mu * mu;
            smu[r] = mu;
            srs[r] = rsqrtf(var + EPSV);
        }
    }
    __syncthreads();
    {
        const int sl = t & 31, du = t >> 5;
        const int grow = g0 + sl;
        if (grow < BB * NQ) {
            const int bn = grow / MM, mm = grow % MM;
            const float mu = smu[sl], rs = srs[sl];
            float* obase = outp + (size_t)bn * 128 * MM + mm;
            for (int it = 0; it < 32; ++it) {
                int dd = it * 4 + du;
                obase[(size_t)dd * MM] = (zt[sl * 132 + dd] - mu) * rs * gam[dd] + bet[dd];
            }
        }
    }
}

extern "C" void kernel_launch(void* const* d_in, const int* in_sizes, int n_in,
                              void* d_out, int out_size, void* d_ws, size_t ws_size,
                              hipStream_t stream) {
    const float* q      = (const float*)d_in[0];
    const float* k      = (const float*)d_in[1];
    const float* v      = (const float*)d_in[2];
    const float* skip   = (const float*)d_in[3];
    const float* ln_q_g = (const float*)d_in[4];
    const float* ln_q_b = (const float*)d_in[5];
    const float* wq     = (const float*)d_in[6];
    const float* bq     = (const float*)d_in[7];
    const float* ln_k_g = (const float*)d_in[8];
    const float* ln_k_b = (const float*)d_in[9];
    const float* wk     = (const float*)d_in[10];
    const float* bk     = (const float*)d_in[11];
    const float* ln_v_g = (const float*)d_in[12];
    const float* ln_v_b = (const float*)d_in[13];
    const float* wv     = (const float*)d_in[14];
    const float* bv     = (const float*)d_in[15];
    const float* proj_w = (const float*)d_in[16];
    const float* proj_b = (const float*)d_in[17];
    const float* pre_g  = (const float*)d_in[18];
    const float* pre_b  = (const float*)d_in[19];
    const float* mlp_w1 = (const float*)d_in[20];
    const float* mlp_b1 = (const float*)d_in[21];
    const float* mlp_w2 = (const float*)d_in[22];
    const float* mlp_b2 = (const float*)d_in[23];
    const float* post_g = (const float*)d_in[24];
    const float* post_b = (const float*)d_in[25];

    float* ws   = (float*)d_ws;
    float* outp = (float*)d_out;

    u16* qh   = (u16*)(ws + OFF_QH);
    u16* kh   = (u16*)(ws + OFF_KH);
    u16* vh   = (u16*)(ws + OFF_VH);
    float* pacc = ws + OFF_PACC;
    float* pl   = ws + OFF_PL;
    float* a    = ws + OFF_A;
    float* z0   = ws + OFF_Z0;
    float* zn   = ws + OFF_ZN;
    float* hmid = ws + OFF_HMID;

    k_lnproj<<<235, 128, 0, stream>>>(q, MM, BB * NQ, ln_q_g, ln_q_b, wq, bq, QPRESCALE, qh);
    k_lnproj<<<630, 128, 0, stream>>>(k, HWSZ, BB * NK, ln_k_g, ln_k_b, wk, bk, 1.0f, kh);
    k_lnproj<<<630, 128, 0, stream>>>(v, HWSZ, BB * NK, ln_v_g, ln_v_b, wv, bv, 1.0f, vh);
    k_attn_mfma<<<BB * HEADS * NQT128 * KC, 256, 0, stream>>>(qh, kh, vh, pacc, pl);
    k_attn_combine<<<3750, 256, 0, stream>>>(pacc, pl, a);
    k_gemm_a<<<235, 128, 0, stream>>>(a, proj_w, proj_b, z0);
    k_skip_ln<<<235, 128, 0, stream>>>(z0, skip, pre_g, pre_b, zn);
    k_mlp1<<<235, 256, 0, stream>>>(zn, mlp_w1, mlp_b1, hmid);
    k_mlp2<<<235, 128, 0, stream>>>(hmid, zn, mlp_w2, mlp_b2, post_g, post_b, outp);
}

// Round 4
// 224.217 us; speedup vs baseline: 6.4210x; 1.8204x over previous
//
#include <hip/hip_runtime.h>
#include <hip/hip_bf16.h>
#include <math.h>

typedef __attribute__((ext_vector_type(8))) short bf16x8;
typedef __attribute__((ext_vector_type(4))) float f32x4;
typedef __attribute__((ext_vector_type(16))) float f32x16;
typedef unsigned short u16;
typedef unsigned int u32;

#define BB 2
#define NN 6
#define MM 625
#define HWSZ 1680
#define NQ 3750
#define NK 10080
#define HEADS 4
#define EPSV 1e-5f
#define KC 5
#define KCHUNK 2016
#define ITERS 63             // KCHUNK/32
#define NQT128 30            // ceil(3750/128)
#define QPRESCALE 0.25503489f   // (1/sqrt(32)) * log2(e)

// ---- workspace offsets (floats) ----
#define OFF_QH   0          // bf16 960000  u16 -> 480000 fl
#define OFF_KH   480000     // bf16 2580480 u16 -> 1290240 fl
#define OFF_VH   1770240
#define OFF_PACC 3060480    // 2*4*5*3750*32 = 4800000 fl
#define OFF_PL   7860480    // 150000 fl
#define OFF_A    8010480    // bf16 960000 u16 -> 480000 fl
#define OFF_ZN   8490480    // 480000 fl
#define OFF_HMID 8970480    // 960000 fl
#define OFF_WTB  9930480    // 131072 u16 -> 65536 fl ; end 9996016

// u16 offsets inside WTB
#define WT_Q    0
#define WT_K    16384
#define WT_V    32768
#define WT_PROJ 49152
#define WT_W1   65536      // [256][128]
#define WT_W2   98304      // [128][256]

#define VEXP(d, s_) asm("v_exp_f32 %0, %1\n\ts_nop 1" : "=v"(d) : "v"(s_))

__device__ inline u16 f2bf(float f) {
    __hip_bfloat16 h = __float2bfloat16(f);
    return *reinterpret_cast<u16*>(&h);
}
__device__ inline float bf2f(u16 u) {
    u32 x = ((u32)u) << 16;
    return *reinterpret_cast<float*>(&x);
}
__device__ inline bf16x8 mk_frag(u32 a, u32 b, u32 c, u32 d) {
    union { u32 u[4]; bf16x8 v; } x;
    x.u[0] = a; x.u[1] = b; x.u[2] = c; x.u[3] = d;
    return x.v;
}

// weights -> bf16 transposed
__global__ void __launch_bounds__(256) k_prep(
        const float* __restrict__ wq, const float* __restrict__ wk,
        const float* __restrict__ wv, const float* __restrict__ pw,
        const float* __restrict__ w1, const float* __restrict__ w2,
        u16* __restrict__ wtb) {
    int idx = blockIdx.x * 256 + threadIdx.x;   // 131072 exact
    float v;
    if (idx < 65536) {
        const float* src = (idx < 16384) ? wq : (idx < 32768) ? wk
                         : (idx < 49152) ? wv : pw;
        int r = idx & 16383;
        int c = r >> 7, kk = r & 127;
        v = src[kk * 128 + c];
    } else if (idx < 98304) {
        int r = idx - 65536;
        int c = r >> 7, kk = r & 127;
        v = w1[kk * 256 + c];
    } else {
        int r = idx - 98304;
        int c = r >> 8, kk = r & 255;
        v = w2[kk * 128 + c];
    }
    wtb[idx] = f2bf(v);
}

// LN (over 128 ch, channel-strided input) + MFMA 128x128 projection -> bf16.
__global__ void __launch_bounds__(128) k_lnproj(const float* __restrict__ x, int S, int rows,
        const float* __restrict__ gam, const float* __restrict__ bet,
        const u16* __restrict__ wt, const float* __restrict__ bias,
        float oscale, u16* __restrict__ outp) {
    __shared__ float xs[32][132];
    __shared__ float smu[32], srs[32];
    const int t = threadIdx.x;
    const int g0 = blockIdx.x * 32;
    {   // transposed coalesced load
        const int sl = t & 31, du = t >> 5;
        const int grow = g0 + sl;
        const bool vload = grow < rows;
        const int bn = grow / S, ss = grow % S;
        const float* xbase = x + (size_t)bn * 128 * S + ss;
        for (int it = 0; it < 32; ++it) {
            int dd = it * 4 + du;
            xs[sl][dd] = vload ? xbase[(size_t)dd * S] : 0.f;
        }
    }
    __syncthreads();
    {   // stats, 4 threads/row
        const int r = t >> 2, p = t & 3;
        float sum = 0.f, sq = 0.f;
        for (int j = 0; j < 32; ++j) {
            float v = xs[r][p + 4 * j];
            sum += v; sq += v * v;
        }
        sum += __shfl_xor(sum, 1); sq += __shfl_xor(sq, 1);
        sum += __shfl_xor(sum, 2); sq += __shfl_xor(sq, 2);
        if (p == 0) {
            float mu = sum * (1.f / 128.f);
            float var = sq * (1.f / 128.f) - mu * mu;
            smu[r] = mu;
            srs[r] = rsqrtf(var + EPSV);
        }
    }
    __syncthreads();
    {   // normalize in LDS
        const float gv = gam[t], bv = bet[t];
        for (int rr = 0; rr < 32; ++rr)
            xs[rr][t] = (xs[rr][t] - smu[rr]) * srs[rr] * gv + bv;
    }
    __syncthreads();
    // MFMA GEMM: wave wid covers cols wid*64..+63
    const int lane = t & 63, wid = t >> 6;
    const int rl = lane & 31, hi = lane >> 5;
    bf16x8 afrag[8];
    #pragma unroll
    for (int ks = 0; ks < 8; ++ks) {
        float4 u = *(const float4*)&xs[rl][ks * 16 + hi * 8];
        float4 w = *(const float4*)&xs[rl][ks * 16 + hi * 8 + 4];
        u32 d0, d1, d2, d3;
        asm("v_cvt_pk_bf16_f32 %0, %1, %2" : "=v"(d0) : "v"(u.x), "v"(u.y));
        asm("v_cvt_pk_bf16_f32 %0, %1, %2" : "=v"(d1) : "v"(u.z), "v"(u.w));
        asm("v_cvt_pk_bf16_f32 %0, %1, %2" : "=v"(d2) : "v"(w.x), "v"(w.y));
        asm("v_cvt_pk_bf16_f32 %0, %1, %2" : "=v"(d3) : "v"(w.z), "v"(w.w));
        afrag[ks] = mk_frag(d0, d1, d2, d3);
    }
    #pragma unroll
    for (int tile = 0; tile < 2; ++tile) {
        const int c = wid * 64 + tile * 32 + rl;
        f32x16 acc;
        #pragma unroll
        for (int i = 0; i < 16; ++i) acc[i] = 0.f;
        #pragma unroll
        for (int ks = 0; ks < 8; ++ks) {
            bf16x8 bfrag = *(const bf16x8*)(wt + (size_t)c * 128 + ks * 16 + hi * 8);
            acc = __builtin_amdgcn_mfma_f32_32x32x16_bf16(afrag[ks], bfrag, acc, 0, 0, 0);
        }
        const float bb = bias[c];
        #pragma unroll
        for (int reg = 0; reg < 16; ++reg) {
            int row = (reg & 3) + 8 * (reg >> 2) + 4 * hi;
            int grow = g0 + row;
            if (grow < rows) outp[(size_t)grow * 128 + c] = f2bf((acc[reg] + bb) * oscale);
        }
    }
}

// MFMA flash attention partial, 32x32 swapped-QK^T, in-register softmax.
__global__ void __launch_bounds__(256) k_attn_mfma(
        const u16* __restrict__ qh, const u16* __restrict__ kh, const u16* __restrict__ vh,
        float* __restrict__ pacc, float* __restrict__ pl) {
    __shared__ u16 Vs[32 * 40];       // V^T tile: [dh 32][keys 32, stride 40]
    const int t = threadIdx.x;
    const int lane = t & 63, wid = t >> 6;
    const int rl = lane & 31, hi = lane >> 5;
    int bid = blockIdx.x;
    const int kc = bid % KC; bid /= KC;
    const int qt = bid % NQT128; bid /= NQT128;
    const int h = bid % HEADS;
    const int b = bid / HEADS;
    const int q0w = qt * 128 + wid * 32;

    int qrow = q0w + rl; if (qrow > NQ - 1) qrow = NQ - 1;
    const u16* qp = qh + ((size_t)b * NQ + qrow) * 128 + h * 32;
    const bf16x8 qf0 = *(const bf16x8*)(qp + hi * 8);
    const bf16x8 qf1 = *(const bf16x8*)(qp + 16 + hi * 8);

    const u16* kbase = kh + (size_t)b * NK * 128 + h * 32;
    const u16* vbase = vh + (size_t)b * NK * 128 + h * 32;
    const int kstart = kc * KCHUNK;

    const int vkey = t & 31, vdhg = t >> 5;

    f32x16 acc;
    #pragma unroll
    for (int i = 0; i < 16; ++i) acc[i] = 0.f;
    f32x16 zero16;
    #pragma unroll
    for (int i = 0; i < 16; ++i) zero16[i] = 0.f;
    float lsum = 0.f;

    bf16x8 kf0 = *(const bf16x8*)(kbase + (size_t)(kstart + rl) * 128 + hi * 8);
    bf16x8 kf1 = *(const bf16x8*)(kbase + (size_t)(kstart + rl) * 128 + 16 + hi * 8);
    ushort4 vld = *(const ushort4*)(vbase + (size_t)(kstart + vkey) * 128 + vdhg * 4);

    for (int ii = 0; ii < ITERS; ++ii) {
        __syncthreads();
        {
            u16* vs = &Vs[vdhg * 4 * 40 + vkey];
            vs[0]   = vld.x;
            vs[40]  = vld.y;
            vs[80]  = vld.z;
            vs[120] = vld.w;
        }
        int knext = (ii + 1 < ITERS) ? kstart + (ii + 1) * 32 : kstart;
        ushort4 vnx = *(const ushort4*)(vbase + (size_t)(knext + vkey) * 128 + vdhg * 4);
        bf16x8 kn0 = *(const bf16x8*)(kbase + (size_t)(knext + rl) * 128 + hi * 8);
        bf16x8 kn1 = *(const bf16x8*)(kbase + (size_t)(knext + rl) * 128 + 16 + hi * 8);

        f32x16 s = __builtin_amdgcn_mfma_f32_32x32x16_bf16(kf0, qf0, zero16, 0, 0, 0);
        s = __builtin_amdgcn_mfma_f32_32x32x16_bf16(kf1, qf1, s, 0, 0, 0);

        u32 dw0, dw1, dw2, dw3, dw4, dw5, dw6, dw7;
        {
            float pa, pb;
            VEXP(pa, s[0]);  VEXP(pb, s[1]);  lsum += pa + pb;
            asm("v_cvt_pk_bf16_f32 %0, %1, %2" : "=v"(dw0) : "v"(pa), "v"(pb));
            VEXP(pa, s[2]);  VEXP(pb, s[3]);  lsum += pa + pb;
            asm("v_cvt_pk_bf16_f32 %0, %1, %2" : "=v"(dw1) : "v"(pa), "v"(pb));
            VEXP(pa, s[4]);  VEXP(pb, s[5]);  lsum += pa + pb;
            asm("v_cvt_pk_bf16_f32 %0, %1, %2" : "=v"(dw2) : "v"(pa), "v"(pb));
            VEXP(pa, s[6]);  VEXP(pb, s[7]);  lsum += pa + pb;
            asm("v_cvt_pk_bf16_f32 %0, %1, %2" : "=v"(dw3) : "v"(pa), "v"(pb));
            VEXP(pa, s[8]);  VEXP(pb, s[9]);  lsum += pa + pb;
            asm("v_cvt_pk_bf16_f32 %0, %1, %2" : "=v"(dw4) : "v"(pa), "v"(pb));
            VEXP(pa, s[10]); VEXP(pb, s[11]); lsum += pa + pb;
            asm("v_cvt_pk_bf16_f32 %0, %1, %2" : "=v"(dw5) : "v"(pa), "v"(pb));
            VEXP(pa, s[12]); VEXP(pb, s[13]); lsum += pa + pb;
            asm("v_cvt_pk_bf16_f32 %0, %1, %2" : "=v"(dw6) : "v"(pa), "v"(pb));
            VEXP(pa, s[14]); VEXP(pb, s[15]); lsum += pa + pb;
            asm("v_cvt_pk_bf16_f32 %0, %1, %2" : "=v"(dw7) : "v"(pa), "v"(pb));
        }
        asm("v_permlane32_swap_b32 %0, %1" : "+v"(dw0), "+v"(dw2));
        asm("v_permlane32_swap_b32 %0, %1" : "+v"(dw1), "+v"(dw3));
        asm("v_permlane32_swap_b32 %0, %1" : "+v"(dw4), "+v"(dw6));
        asm("v_permlane32_swap_b32 %0, %1" : "+v"(dw5), "+v"(dw7));
        const bf16x8 pfrag0 = mk_frag(dw0, dw1, dw2, dw3);
        const bf16x8 pfrag1 = mk_frag(dw4, dw5, dw6, dw7);

        __syncthreads();
        const bf16x8 vf0 = *(const bf16x8*)&Vs[rl * 40 + hi * 8];
        const bf16x8 vf1 = *(const bf16x8*)&Vs[rl * 40 + 16 + hi * 8];
        acc = __builtin_amdgcn_mfma_f32_32x32x16_bf16(pfrag0, vf0, acc, 0, 0, 0);
        acc = __builtin_amdgcn_mfma_f32_32x32x16_bf16(pfrag1, vf1, acc, 0, 0, 0);

        kf0 = kn0; kf1 = kn1; vld = vnx;
    }

    float ltot = lsum + __shfl_xor(lsum, 32);

    const int pi = (b * HEADS + h) * KC + kc;
    #pragma unroll
    for (int reg = 0; reg < 16; ++reg) {
        int qloc = (reg & 3) + 8 * (reg >> 2) + 4 * hi;
        int qq = q0w + qloc;
        if (qq < NQ) pacc[((size_t)pi * NQ + qq) * 32 + rl] = acc[reg];
    }
    if (hi == 0) {
        int qq = q0w + rl;
        if (qq < NQ) pl[(size_t)pi * NQ + qq] = ltot;
    }
}

__global__ void __launch_bounds__(256) k_attn_combine(const float* __restrict__ pacc,
        const float* __restrict__ pl, u16* __restrict__ a) {
    const int idx = blockIdx.x * 256 + threadIdx.x;   // B*H*NQ*32, exact
    const int j = idx & 31;
    const int qq = (idx >> 5) % NQ;
    const int bh = idx / (32 * NQ);
    const int b = bh / HEADS, h = bh % HEADS;
    float L = 0.f, val = 0.f;
    #pragma unroll
    for (int kc = 0; kc < KC; ++kc) {
        size_t pi = (size_t)(bh * KC + kc) * NQ + qq;
        L += pl[pi];
        val += pacc[pi * 32 + j];
    }
    a[((size_t)b * NQ + qq) * 128 + h * 32 + j] = f2bf(val / L);
}

// z0 = a @ projT + b ; + skip ; pre-LN -> zn (bf16)
__global__ void __launch_bounds__(256) k_projskip(
        const u16* __restrict__ a, const u16* __restrict__ wt,
        const float* __restrict__ bias, const float* __restrict__ skip,
        const float* __restrict__ gam, const float* __restrict__ bet,
        u16* __restrict__ zn) {
    __shared__ float zs[32][132];
    __shared__ float smu[32], srs[32];
    const int t = threadIdx.x;
    const int g0 = blockIdx.x * 32;
    const int lane = t & 63, wid = t >> 6;
    const int rl = lane & 31, hi = lane >> 5;
    const int rows = BB * NQ;
    int arow = g0 + rl; if (arow > rows - 1) arow = rows - 1;
    const int c = wid * 32 + rl;
    f32x16 acc;
    #pragma unroll
    for (int i = 0; i < 16; ++i) acc[i] = 0.f;
    #pragma unroll
    for (int ks = 0; ks < 8; ++ks) {
        bf16x8 af = *(const bf16x8*)(a + (size_t)arow * 128 + ks * 16 + hi * 8);
        bf16x8 bf = *(const bf16x8*)(wt + (size_t)c * 128 + ks * 16 + hi * 8);
        acc = __builtin_amdgcn_mfma_f32_32x32x16_bf16(af, bf, acc, 0, 0, 0);
    }
    const float bb = bias[c];
    #pragma unroll
    for (int reg = 0; reg < 16; ++reg) {
        int row = (reg & 3) + 8 * (reg >> 2) + 4 * hi;
        zs[row][c] = acc[reg] + bb;
    }
    __syncthreads();
    {   // skip add (channel-strided)
        const int sl = t & 31, du = t >> 5;   // du 0..7
        const int grow = g0 + sl;
        if (grow < rows) {
            const int bn = grow / MM, mm = grow % MM;
            const float* sbase = skip + (size_t)bn * 128 * MM + mm;
            for (int it = 0; it < 16; ++it) {
                int dd = it * 8 + du;
                zs[sl][dd] += sbase[(size_t)dd * MM];
            }
        }
    }
    __syncthreads();
    {   // stats, 8 threads/row
        const int r = t >> 3, p = t & 7;
        float sum = 0.f, sq = 0.f;
        for (int j = 0; j < 16; ++j) {
            float v = zs[r][p + 8 * j];
            sum += v; sq += v * v;
        }
        sum += __shfl_xor(sum, 1); sq += __shfl_xor(sq, 1);
        sum += __shfl_xor(sum, 2); sq += __shfl_xor(sq, 2);
        sum += __shfl_xor(sum, 4); sq += __shfl_xor(sq, 4);
        if (p == 0) {
            float mu = sum * (1.f / 128.f);
            float var = sq * (1.f / 128.f) - mu * mu;
            smu[r] = mu; srs[r] = rsqrtf(var + EPSV);
        }
    }
    __syncthreads();
    {
        const int cc = t & 127, rh = t >> 7;
        const float gv = gam[cc], bv = bet[cc];
        for (int i = 0; i < 16; ++i) {
            int rr = rh * 16 + i;
            int grow = g0 + rr;
            if (grow < rows)
                zn[(size_t)grow * 128 + cc] = f2bf((zs[rr][cc] - smu[rr]) * srs[rr] * gv + bv);
        }
    }
}

// hmid = gelu(zn @ w1T + b1) -> bf16
__global__ void __launch_bounds__(256) k_mlp1(
        const u16* __restrict__ zn, const u16* __restrict__ wt,
        const float* __restrict__ bias, u16* __restrict__ hmid) {
    const int t = threadIdx.x;
    const int g0 = blockIdx.x * 32;
    const int lane = t & 63, wid = t >> 6;
    const int rl = lane & 31, hi = lane >> 5;
    const int rows = BB * NQ;
    int arow = g0 + rl; if (arow > rows - 1) arow = rows - 1;
    bf16x8 afrag[8];
    #pragma unroll
    for (int ks = 0; ks < 8; ++ks)
        afrag[ks] = *(const bf16x8*)(zn + (size_t)arow * 128 + ks * 16 + hi * 8);
    #pragma unroll
    for (int tile = 0; tile < 2; ++tile) {
        const int c = wid * 64 + tile * 32 + rl;
        f32x16 acc;
        #pragma unroll
        for (int i = 0; i < 16; ++i) acc[i] = 0.f;
        #pragma unroll
        for (int ks = 0; ks < 8; ++ks) {
            bf16x8 bf = *(const bf16x8*)(wt + (size_t)c * 128 + ks * 16 + hi * 8);
            acc = __builtin_amdgcn_mfma_f32_32x32x16_bf16(afrag[ks], bf, acc, 0, 0, 0);
        }
        const float bb = bias[c];
        #pragma unroll
        for (int reg = 0; reg < 16; ++reg) {
            int row = (reg & 3) + 8 * (reg >> 2) + 4 * hi;
            int grow = g0 + row;
            if (grow < rows) {
                float x = acc[reg] + bb;
                float gl = 0.5f * x * (1.f + erff(x * 0.70710678118654752f));
                hmid[(size_t)grow * 256 + c] = f2bf(gl);
            }
        }
    }
}

// z2 = zn + hmid @ w2T + b2 ; post-LN ; transposed store fp32
__global__ void __launch_bounds__(256) k_mlp2(
        const u16* __restrict__ hmid, const u16* __restrict__ wt,
        const float* __restrict__ bias, const u16* __restrict__ zn,
        const float* __restrict__ gam, const float* __restrict__ bet,
        float* __restrict__ outp) {
    __shared__ float zt[32][132];
    __shared__ float smu[32], srs[32];
    const int t = threadIdx.x;
    const int g0 = blockIdx.x * 32;
    const int lane = t & 63, wid = t >> 6;
    const int rl = lane & 31, hi = lane >> 5;
    const int rows = BB * NQ;
    int arow = g0 + rl; if (arow > rows - 1) arow = rows - 1;
    const int c = wid * 32 + rl;
    f32x16 acc;
    #pragma unroll
    for (int i = 0; i < 16; ++i) acc[i] = 0.f;
    #pragma unroll
    for (int ks = 0; ks < 16; ++ks) {
        bf16x8 af = *(const bf16x8*)(hmid + (size_t)arow * 256 + ks * 16 + hi * 8);
        bf16x8 bf = *(const bf16x8*)(wt + (size_t)c * 256 + ks * 16 + hi * 8);
        acc = __builtin_amdgcn_mfma_f32_32x32x16_bf16(af, bf, acc, 0, 0, 0);
    }
    const float bb = bias[c];
    #pragma unroll
    for (int reg = 0; reg < 16; ++reg) {
        int row = (reg & 3) + 8 * (reg >> 2) + 4 * hi;
        zt[row][c] = acc[reg] + bb;
    }
    __syncthreads();
    {   // + zn residual
        const int cc = t & 127, rh = t >> 7;
        for (int i = 0; i < 16; ++i) {
            int rr = rh * 16 + i;
            int grow = g0 + rr;
            u16 zv = (grow < rows) ? zn[(size_t)grow * 128 + cc] : (u16)0;
            zt[rr][cc] += bf2f(zv);
        }
    }
    __syncthreads();
    {   // stats, 8 threads/row
        const int r = t >> 3, p = t & 7;
        float sum = 0.f, sq = 0.f;
        for (int j = 0; j < 16; ++j) {
            float v = zt[r][p + 8 * j];
            sum += v; sq += v * v;
        }
        sum += __shfl_xor(sum, 1); sq += __shfl_xor(sq, 1);
        sum += __shfl_xor(sum, 2); sq += __shfl_xor(sq, 2);
        sum += __shfl_xor(sum, 4); sq += __shfl_xor(sq, 4);
        if (p == 0) {
            float mu = sum * (1.f / 128.f);
            float var = sq * (1.f / 128.f) - mu * mu;
            smu[r] = mu; srs[r] = rsqrtf(var + EPSV);
        }
    }
    __syncthreads();
    {   // transposed store
        const int sl = t & 31, du = t >> 5;   // du 0..7
        const int grow = g0 + sl;
        if (grow < rows) {
            const int bn = grow / MM, mm = grow % MM;
            const float mu = smu[sl], rs = srs[sl];
            float* obase = outp + (size_t)bn * 128 * MM + mm;
            for (int it = 0; it < 16; ++it) {
                int dd = it * 8 + du;
                obase[(size_t)dd * MM] = (zt[sl][dd] - mu) * rs * gam[dd] + bet[dd];
            }
        }
    }
}

extern "C" void kernel_launch(void* const* d_in, const int* in_sizes, int n_in,
                              void* d_out, int out_size, void* d_ws, size_t ws_size,
                              hipStream_t stream) {
    const float* q      = (const float*)d_in[0];
    const float* k      = (const float*)d_in[1];
    const float* v      = (const float*)d_in[2];
    const float* skip   = (const float*)d_in[3];
    const float* ln_q_g = (const float*)d_in[4];
    const float* ln_q_b = (const float*)d_in[5];
    const float* wq     = (const float*)d_in[6];
    const float* bq     = (const float*)d_in[7];
    const float* ln_k_g = (const float*)d_in[8];
    const float* ln_k_b = (const float*)d_in[9];
    const float* wk     = (const float*)d_in[10];
    const float* bk     = (const float*)d_in[11];
    const float* ln_v_g = (const float*)d_in[12];
    const float* ln_v_b = (const float*)d_in[13];
    const float* wv     = (const float*)d_in[14];
    const float* bv     = (const float*)d_in[15];
    const float* proj_w = (const float*)d_in[16];
    const float* proj_b = (const float*)d_in[17];
    const float* pre_g  = (const float*)d_in[18];
    const float* pre_b  = (const float*)d_in[19];
    const float* mlp_w1 = (const float*)d_in[20];
    const float* mlp_b1 = (const float*)d_in[21];
    const float* mlp_w2 = (const float*)d_in[22];
    const float* mlp_b2 = (const float*)d_in[23];
    const float* post_g = (const float*)d_in[24];
    const float* post_b = (const float*)d_in[25];

    float* ws   = (float*)d_ws;
    float* outp = (float*)d_out;

    u16* qh   = (u16*)(ws + OFF_QH);
    u16* kh   = (u16*)(ws + OFF_KH);
    u16* vh   = (u16*)(ws + OFF_VH);
    float* pacc = ws + OFF_PACC;
    float* pl   = ws + OFF_PL;
    u16* a    = (u16*)(ws + OFF_A);
    u16* zn   = (u16*)(ws + OFF_ZN);
    u16* hmid = (u16*)(ws + OFF_HMID);
    u16* wtb  = (u16*)(ws + OFF_WTB);

    k_prep<<<512, 256, 0, stream>>>(wq, wk, wv, proj_w, mlp_w1, mlp_w2, wtb);
    k_lnproj<<<235, 128, 0, stream>>>(q, MM, BB * NQ, ln_q_g, ln_q_b, wtb + WT_Q, bq, QPRESCALE, qh);
    k_lnproj<<<630, 128, 0, stream>>>(k, HWSZ, BB * NK, ln_k_g, ln_k_b, wtb + WT_K, bk, 1.0f, kh);
    k_lnproj<<<630, 128, 0, stream>>>(v, HWSZ, BB * NK, ln_v_g, ln_v_b, wtb + WT_V, bv, 1.0f, vh);
    k_attn_mfma<<<BB * HEADS * NQT128 * KC, 256, 0, stream>>>(qh, kh, vh, pacc, pl);
    k_attn_combine<<<3750, 256, 0, stream>>>(pacc, pl, a);
    k_projskip<<<235, 256, 0, stream>>>(a, wtb + WT_PROJ, proj_b, skip, pre_g, pre_b, zn);
    k_mlp1<<<235, 256, 0, stream>>>(zn, wtb + WT_W1, mlp_b1, hmid);
    k_mlp2<<<235, 256, 0, stream>>>(hmid, wtb + WT_W2, mlp_b2, zn, post_g, post_b, outp);
}

// Round 5
// 194.092 us; speedup vs baseline: 7.4176x; 1.1552x over previous
//
#include <hip/hip_runtime.h>
#include <hip/hip_bf16.h>
#include <math.h>

typedef __attribute__((ext_vector_type(8))) short bf16x8;
typedef __attribute__((ext_vector_type(4))) float f32x4;
typedef __attribute__((ext_vector_type(16))) float f32x16;
typedef unsigned short u16;
typedef unsigned int u32;

#define BB 2
#define NN 6
#define MM 625
#define HWSZ 1680
#define NQ 3750
#define NK 10080
#define HEADS 4
#define EPSV 1e-5f
#define KC 9
#define KCHUNK 1120
#define ITERS 35             // KCHUNK/32
#define NQT256 15            // ceil(3750/256)
#define QPRESCALE 0.25503489f   // (1/sqrt(32)) * log2(e)

// ---- workspace offsets (floats) ----
#define OFF_QH   0          // bf16 960000  u16 -> 480000 fl
#define OFF_KH   480000     // bf16 2580480 u16 -> 1290240 fl
#define OFF_VH   1770240
#define OFF_PACC 3060480    // bf16 2*4*9*3750*32 = 8640000 u16 -> 4320000 fl
#define OFF_PL   7380480    // 270000 fl
#define OFF_A    7650480    // bf16 960000 u16 -> 480000 fl
#define OFF_ZN   8130480
#define OFF_HMID 8610480    // bf16 1920000 u16 -> 960000 fl
#define OFF_WTB  9570480    // 131072 u16 -> 65536 fl ; end 9636016

// u16 offsets inside WTB
#define WT_Q    0
#define WT_K    16384
#define WT_V    32768
#define WT_PROJ 49152
#define WT_W1   65536      // [256][128]
#define WT_W2   98304      // [128][256]

#define VEXP(d, s_) asm("v_exp_f32 %0, %1\n\ts_nop 1" : "=v"(d) : "v"(s_))
#define CVTPK(d, a, b) asm("v_cvt_pk_bf16_f32 %0, %1, %2" : "=v"(d) : "v"(a), "v"(b))

__device__ inline u16 f2bf(float f) {
    __hip_bfloat16 h = __float2bfloat16(f);
    return *reinterpret_cast<u16*>(&h);
}
__device__ inline float bf2f(u16 u) {
    u32 x = ((u32)u) << 16;
    return *reinterpret_cast<float*>(&x);
}
__device__ inline bf16x8 mk_frag(u32 a, u32 b, u32 c, u32 d) {
    union { u32 u[4]; bf16x8 v; } x;
    x.u[0] = a; x.u[1] = b; x.u[2] = c; x.u[3] = d;
    return x.v;
}

// weights -> bf16 transposed
__global__ void __launch_bounds__(256) k_prep(
        const float* __restrict__ wq, const float* __restrict__ wk,
        const float* __restrict__ wv, const float* __restrict__ pw,
        const float* __restrict__ w1, const float* __restrict__ w2,
        u16* __restrict__ wtb) {
    int idx = blockIdx.x * 256 + threadIdx.x;   // 131072 exact
    float v;
    if (idx < 65536) {
        const float* src = (idx < 16384) ? wq : (idx < 32768) ? wk
                         : (idx < 49152) ? wv : pw;
        int r = idx & 16383;
        int c = r >> 7, kk = r & 127;
        v = src[kk * 128 + c];
    } else if (idx < 98304) {
        int r = idx - 65536;
        int c = r >> 7, kk = r & 127;
        v = w1[kk * 256 + c];
    } else {
        int r = idx - 98304;
        int c = r >> 8, kk = r & 255;
        v = w2[kk * 128 + c];
    }
    wtb[idx] = f2bf(v);
}

// LN (over 128 ch, channel-strided input) + MFMA 128x128 projection -> bf16.
__global__ void __launch_bounds__(128) k_lnproj(const float* __restrict__ x, int S, int rows,
        const float* __restrict__ gam, const float* __restrict__ bet,
        const u16* __restrict__ wt, const float* __restrict__ bias,
        float oscale, u16* __restrict__ outp) {
    __shared__ float xs[32][132];
    __shared__ float smu[32], srs[32];
    const int t = threadIdx.x;
    const int g0 = blockIdx.x * 32;
    {   // transposed coalesced load
        const int sl = t & 31, du = t >> 5;
        const int grow = g0 + sl;
        const bool vload = grow < rows;
        const int bn = grow / S, ss = grow % S;
        const float* xbase = x + (size_t)bn * 128 * S + ss;
        for (int it = 0; it < 32; ++it) {
            int dd = it * 4 + du;
            xs[sl][dd] = vload ? xbase[(size_t)dd * S] : 0.f;
        }
    }
    __syncthreads();
    {   // stats, 4 threads/row
        const int r = t >> 2, p = t & 3;
        float sum = 0.f, sq = 0.f;
        for (int j = 0; j < 32; ++j) {
            float v = xs[r][p + 4 * j];
            sum += v; sq += v * v;
        }
        sum += __shfl_xor(sum, 1); sq += __shfl_xor(sq, 1);
        sum += __shfl_xor(sum, 2); sq += __shfl_xor(sq, 2);
        if (p == 0) {
            float mu = sum * (1.f / 128.f);
            float var = sq * (1.f / 128.f) - mu * mu;
            smu[r] = mu;
            srs[r] = rsqrtf(var + EPSV);
        }
    }
    __syncthreads();
    {   // normalize in LDS
        const float gv = gam[t], bv = bet[t];
        for (int rr = 0; rr < 32; ++rr)
            xs[rr][t] = (xs[rr][t] - smu[rr]) * srs[rr] * gv + bv;
    }
    __syncthreads();
    // MFMA GEMM: wave wid covers cols wid*64..+63
    const int lane = t & 63, wid = t >> 6;
    const int rl = lane & 31, hi = lane >> 5;
    bf16x8 afrag[8];
    #pragma unroll
    for (int ks = 0; ks < 8; ++ks) {
        float4 u = *(const float4*)&xs[rl][ks * 16 + hi * 8];
        float4 w = *(const float4*)&xs[rl][ks * 16 + hi * 8 + 4];
        u32 d0, d1, d2, d3;
        CVTPK(d0, u.x, u.y);
        CVTPK(d1, u.z, u.w);
        CVTPK(d2, w.x, w.y);
        CVTPK(d3, w.z, w.w);
        afrag[ks] = mk_frag(d0, d1, d2, d3);
    }
    #pragma unroll
    for (int tile = 0; tile < 2; ++tile) {
        const int c = wid * 64 + tile * 32 + rl;
        f32x16 acc;
        #pragma unroll
        for (int i = 0; i < 16; ++i) acc[i] = 0.f;
        #pragma unroll
        for (int ks = 0; ks < 8; ++ks) {
            bf16x8 bfrag = *(const bf16x8*)(wt + (size_t)c * 128 + ks * 16 + hi * 8);
            acc = __builtin_amdgcn_mfma_f32_32x32x16_bf16(afrag[ks], bfrag, acc, 0, 0, 0);
        }
        const float bb = bias[c];
        #pragma unroll
        for (int reg = 0; reg < 16; ++reg) {
            int row = (reg & 3) + 8 * (reg >> 2) + 4 * hi;
            int grow = g0 + row;
            if (grow < rows) outp[(size_t)grow * 128 + c] = f2bf((acc[reg] + bb) * oscale);
        }
    }
}

// MFMA flash attention partial: 32x32 swapped-QK^T, in-register softmax,
// 2 q-tiles per wave, double-buffered V staging, ONE barrier per iter.
__global__ void __launch_bounds__(256) k_attn_mfma(
        const u16* __restrict__ qh, const u16* __restrict__ kh, const u16* __restrict__ vh,
        u16* __restrict__ pacc, float* __restrict__ pl) {
    __shared__ u16 Vs[2][32 * 40];    // V^T tiles: [dh 32][keys 32, stride 40]
    const int t = threadIdx.x;
    const int lane = t & 63, wid = t >> 6;
    const int rl = lane & 31, hi = lane >> 5;
    int bid = blockIdx.x;
    const int kc = bid % KC; bid /= KC;
    const int qt = bid % NQT256; bid /= NQT256;
    const int h = bid % HEADS;
    const int b = bid / HEADS;
    const int q0A = qt * 256 + wid * 32;
    const int q0B = q0A + 128;

    int qrowA = q0A + rl; if (qrowA > NQ - 1) qrowA = NQ - 1;
    int qrowB = q0B + rl; if (qrowB > NQ - 1) qrowB = NQ - 1;
    const u16* qpA = qh + ((size_t)b * NQ + qrowA) * 128 + h * 32;
    const u16* qpB = qh + ((size_t)b * NQ + qrowB) * 128 + h * 32;
    const bf16x8 qfA0 = *(const bf16x8*)(qpA + hi * 8);
    const bf16x8 qfA1 = *(const bf16x8*)(qpA + 16 + hi * 8);
    const bf16x8 qfB0 = *(const bf16x8*)(qpB + hi * 8);
    const bf16x8 qfB1 = *(const bf16x8*)(qpB + 16 + hi * 8);

    const u16* kbase = kh + (size_t)b * NK * 128 + h * 32;
    const u16* vbase = vh + (size_t)b * NK * 128 + h * 32;
    const int kstart = kc * KCHUNK;

    const int vkey = t & 31, vdhg = t >> 5;

    f32x16 accA, accB, zero16;
    #pragma unroll
    for (int i = 0; i < 16; ++i) { accA[i] = 0.f; accB[i] = 0.f; zero16[i] = 0.f; }
    float lsumA = 0.f, lsumB = 0.f;

    // prologue: tile0 V staged; K(0) + V(1) in regs
    ushort4 vld0 = *(const ushort4*)(vbase + (size_t)(kstart + vkey) * 128 + vdhg * 4);
    bf16x8 kf0 = *(const bf16x8*)(kbase + (size_t)(kstart + rl) * 128 + hi * 8);
    bf16x8 kf1 = *(const bf16x8*)(kbase + (size_t)(kstart + rl) * 128 + 16 + hi * 8);
    {
        u16* vs = &Vs[0][vdhg * 4 * 40 + vkey];
        vs[0] = vld0.x; vs[40] = vld0.y; vs[80] = vld0.z; vs[120] = vld0.w;
    }
    int k1 = (ITERS > 1) ? kstart + 32 : kstart;
    ushort4 vheld = *(const ushort4*)(vbase + (size_t)(k1 + vkey) * 128 + vdhg * 4);
    __syncthreads();

    for (int ii = 0; ii < ITERS; ++ii) {
        const int cur = ii & 1;
        // stage NEXT tile's V into the other buffer (garbage on last iter, never read)
        {
            u16* vs = &Vs[cur ^ 1][vdhg * 4 * 40 + vkey];
            vs[0] = vheld.x; vs[40] = vheld.y; vs[80] = vheld.z; vs[120] = vheld.w;
        }
        // issue loads for iter ii+1 compute (K) and iter ii+2 staging (V)
        int kn = (ii + 1 < ITERS) ? kstart + (ii + 1) * 32 : kstart;
        int kn2 = (ii + 2 < ITERS) ? kstart + (ii + 2) * 32 : kstart;
        ushort4 vnext = *(const ushort4*)(vbase + (size_t)(kn2 + vkey) * 128 + vdhg * 4);
        bf16x8 kn0 = *(const bf16x8*)(kbase + (size_t)(kn + rl) * 128 + hi * 8);
        bf16x8 kn1 = *(const bf16x8*)(kbase + (size_t)(kn + rl) * 128 + 16 + hi * 8);

        // QK^T for both q-tiles (shared K-fragments)
        __builtin_amdgcn_s_setprio(1);
        f32x16 sA = __builtin_amdgcn_mfma_f32_32x32x16_bf16(kf0, qfA0, zero16, 0, 0, 0);
        sA = __builtin_amdgcn_mfma_f32_32x32x16_bf16(kf1, qfA1, sA, 0, 0, 0);
        f32x16 sB = __builtin_amdgcn_mfma_f32_32x32x16_bf16(kf0, qfB0, zero16, 0, 0, 0);
        sB = __builtin_amdgcn_mfma_f32_32x32x16_bf16(kf1, qfB1, sB, 0, 0, 0);
        __builtin_amdgcn_s_setprio(0);

        // softmax numerators (fixed max=0; Q pre-scaled by SCALE*log2e)
        u32 a0, a1, a2, a3, a4, a5, a6, a7;
        u32 b0, b1, b2, b3, b4, b5, b6, b7;
        {
            float pa, pb;
            VEXP(pa, sA[0]);  VEXP(pb, sA[1]);  lsumA += pa + pb; CVTPK(a0, pa, pb);
            VEXP(pa, sA[2]);  VEXP(pb, sA[3]);  lsumA += pa + pb; CVTPK(a1, pa, pb);
            VEXP(pa, sA[4]);  VEXP(pb, sA[5]);  lsumA += pa + pb; CVTPK(a2, pa, pb);
            VEXP(pa, sA[6]);  VEXP(pb, sA[7]);  lsumA += pa + pb; CVTPK(a3, pa, pb);
            VEXP(pa, sA[8]);  VEXP(pb, sA[9]);  lsumA += pa + pb; CVTPK(a4, pa, pb);
            VEXP(pa, sA[10]); VEXP(pb, sA[11]); lsumA += pa + pb; CVTPK(a5, pa, pb);
            VEXP(pa, sA[12]); VEXP(pb, sA[13]); lsumA += pa + pb; CVTPK(a6, pa, pb);
            VEXP(pa, sA[14]); VEXP(pb, sA[15]); lsumA += pa + pb; CVTPK(a7, pa, pb);
            VEXP(pa, sB[0]);  VEXP(pb, sB[1]);  lsumB += pa + pb; CVTPK(b0, pa, pb);
            VEXP(pa, sB[2]);  VEXP(pb, sB[3]);  lsumB += pa + pb; CVTPK(b1, pa, pb);
            VEXP(pa, sB[4]);  VEXP(pb, sB[5]);  lsumB += pa + pb; CVTPK(b2, pa, pb);
            VEXP(pa, sB[6]);  VEXP(pb, sB[7]);  lsumB += pa + pb; CVTPK(b3, pa, pb);
            VEXP(pa, sB[8]);  VEXP(pb, sB[9]);  lsumB += pa + pb; CVTPK(b4, pa, pb);
            VEXP(pa, sB[10]); VEXP(pb, sB[11]); lsumB += pa + pb; CVTPK(b5, pa, pb);
            VEXP(pa, sB[12]); VEXP(pb, sB[13]); lsumB += pa + pb; CVTPK(b6, pa, pb);
            VEXP(pa, sB[14]); VEXP(pb, sB[15]); lsumB += pa + pb; CVTPK(b7, pa, pb);
        }
        asm("v_permlane32_swap_b32 %0, %1" : "+v"(a0), "+v"(a2));
        asm("v_permlane32_swap_b32 %0, %1" : "+v"(a1), "+v"(a3));
        asm("v_permlane32_swap_b32 %0, %1" : "+v"(a4), "+v"(a6));
        asm("v_permlane32_swap_b32 %0, %1" : "+v"(a5), "+v"(a7));
        asm("v_permlane32_swap_b32 %0, %1" : "+v"(b0), "+v"(b2));
        asm("v_permlane32_swap_b32 %0, %1" : "+v"(b1), "+v"(b3));
        asm("v_permlane32_swap_b32 %0, %1" : "+v"(b4), "+v"(b6));
        asm("v_permlane32_swap_b32 %0, %1" : "+v"(b5), "+v"(b7));
        const bf16x8 pA0 = mk_frag(a0, a1, a2, a3);
        const bf16x8 pA1 = mk_frag(a4, a5, a6, a7);
        const bf16x8 pB0 = mk_frag(b0, b1, b2, b3);
        const bf16x8 pB1 = mk_frag(b4, b5, b6, b7);

        // PV: V-fragments read once, feed both q-tiles
        const bf16x8 vf0 = *(const bf16x8*)&Vs[cur][rl * 40 + hi * 8];
        const bf16x8 vf1 = *(const bf16x8*)&Vs[cur][rl * 40 + 16 + hi * 8];
        __builtin_amdgcn_s_setprio(1);
        accA = __builtin_amdgcn_mfma_f32_32x32x16_bf16(pA0, vf0, accA, 0, 0, 0);
        accA = __builtin_amdgcn_mfma_f32_32x32x16_bf16(pA1, vf1, accA, 0, 0, 0);
        accB = __builtin_amdgcn_mfma_f32_32x32x16_bf16(pB0, vf0, accB, 0, 0, 0);
        accB = __builtin_amdgcn_mfma_f32_32x32x16_bf16(pB1, vf1, accB, 0, 0, 0);
        __builtin_amdgcn_s_setprio(0);

        __syncthreads();   // next iter may overwrite Vs[cur] / read Vs[cur^1]
        kf0 = kn0; kf1 = kn1; vheld = vnext;
    }

    float ltotA = lsumA + __shfl_xor(lsumA, 32);
    float ltotB = lsumB + __shfl_xor(lsumB, 32);

    const int pi = (b * HEADS + h) * KC + kc;
    #pragma unroll
    for (int reg = 0; reg < 16; ++reg) {
        int qloc = (reg & 3) + 8 * (reg >> 2) + 4 * hi;
        int qqA = q0A + qloc;
        int qqB = q0B + qloc;
        if (qqA < NQ) pacc[((size_t)pi * NQ + qqA) * 32 + rl] = f2bf(accA[reg]);
        if (qqB < NQ) pacc[((size_t)pi * NQ + qqB) * 32 + rl] = f2bf(accB[reg]);
    }
    if (hi == 0) {
        int qqA = q0A + rl, qqB = q0B + rl;
        if (qqA < NQ) pl[(size_t)pi * NQ + qqA] = ltotA;
        if (qqB < NQ) pl[(size_t)pi * NQ + qqB] = ltotB;
    }
}

__global__ void __launch_bounds__(256) k_attn_combine(const u16* __restrict__ pacc,
        const float* __restrict__ pl, u16* __restrict__ a) {
    const int idx = blockIdx.x * 256 + threadIdx.x;   // B*H*NQ*32, exact
    const int j = idx & 31;
    const int qq = (idx >> 5) % NQ;
    const int bh = idx / (32 * NQ);
    const int b = bh / HEADS, h = bh % HEADS;
    float L = 0.f, val = 0.f;
    #pragma unroll
    for (int kc = 0; kc < KC; ++kc) {
        size_t pi = (size_t)(bh * KC + kc) * NQ + qq;
        L += pl[pi];
        val += bf2f(pacc[pi * 32 + j]);
    }
    a[((size_t)b * NQ + qq) * 128 + h * 32 + j] = f2bf(val / L);
}

// z0 = a @ projT + b ; + skip ; pre-LN -> zn (bf16)
__global__ void __launch_bounds__(256) k_projskip(
        const u16* __restrict__ a, const u16* __restrict__ wt,
        const float* __restrict__ bias, const float* __restrict__ skip,
        const float* __restrict__ gam, const float* __restrict__ bet,
        u16* __restrict__ zn) {
    __shared__ float zs[32][132];
    __shared__ float smu[32], srs[32];
    const int t = threadIdx.x;
    const int g0 = blockIdx.x * 32;
    const int lane = t & 63, wid = t >> 6;
    const int rl = lane & 31, hi = lane >> 5;
    const int rows = BB * NQ;
    int arow = g0 + rl; if (arow > rows - 1) arow = rows - 1;
    const int c = wid * 32 + rl;
    f32x16 acc;
    #pragma unroll
    for (int i = 0; i < 16; ++i) acc[i] = 0.f;
    #pragma unroll
    for (int ks = 0; ks < 8; ++ks) {
        bf16x8 af = *(const bf16x8*)(a + (size_t)arow * 128 + ks * 16 + hi * 8);
        bf16x8 bf = *(const bf16x8*)(wt + (size_t)c * 128 + ks * 16 + hi * 8);
        acc = __builtin_amdgcn_mfma_f32_32x32x16_bf16(af, bf, acc, 0, 0, 0);
    }
    const float bb = bias[c];
    #pragma unroll
    for (int reg = 0; reg < 16; ++reg) {
        int row = (reg & 3) + 8 * (reg >> 2) + 4 * hi;
        zs[row][c] = acc[reg] + bb;
    }
    __syncthreads();
    {   // skip add (channel-strided)
        const int sl = t & 31, du = t >> 5;   // du 0..7
        const int grow = g0 + sl;
        if (grow < rows) {
            const int bn = grow / MM, mm = grow % MM;
            const float* sbase = skip + (size_t)bn * 128 * MM + mm;
            for (int it = 0; it < 16; ++it) {
                int dd = it * 8 + du;
                zs[sl][dd] += sbase[(size_t)dd * MM];
            }
        }
    }
    __syncthreads();
    {   // stats, 8 threads/row
        const int r = t >> 3, p = t & 7;
        float sum = 0.f, sq = 0.f;
        for (int j = 0; j < 16; ++j) {
            float v = zs[r][p + 8 * j];
            sum += v; sq += v * v;
        }
        sum += __shfl_xor(sum, 1); sq += __shfl_xor(sq, 1);
        sum += __shfl_xor(sum, 2); sq += __shfl_xor(sq, 2);
        sum += __shfl_xor(sum, 4); sq += __shfl_xor(sq, 4);
        if (p == 0) {
            float mu = sum * (1.f / 128.f);
            float var = sq * (1.f / 128.f) - mu * mu;
            smu[r] = mu; srs[r] = rsqrtf(var + EPSV);
        }
    }
    __syncthreads();
    {
        const int cc = t & 127, rh = t >> 7;
        const float gv = gam[cc], bv = bet[cc];
        for (int i = 0; i < 16; ++i) {
            int rr = rh * 16 + i;
            int grow = g0 + rr;
            if (grow < rows)
                zn[(size_t)grow * 128 + cc] = f2bf((zs[rr][cc] - smu[rr]) * srs[rr] * gv + bv);
        }
    }
}

// hmid = gelu(zn @ w1T + b1) -> bf16
__global__ void __launch_bounds__(256) k_mlp1(
        const u16* __restrict__ zn, const u16* __restrict__ wt,
        const float* __restrict__ bias, u16* __restrict__ hmid) {
    const int t = threadIdx.x;
    const int g0 = blockIdx.x * 32;
    const int lane = t & 63, wid = t >> 6;
    const int rl = lane & 31, hi = lane >> 5;
    const int rows = BB * NQ;
    int arow = g0 + rl; if (arow > rows - 1) arow = rows - 1;
    bf16x8 afrag[8];
    #pragma unroll
    for (int ks = 0; ks < 8; ++ks)
        afrag[ks] = *(const bf16x8*)(zn + (size_t)arow * 128 + ks * 16 + hi * 8);
    #pragma unroll
    for (int tile = 0; tile < 2; ++tile) {
        const int c = wid * 64 + tile * 32 + rl;
        f32x16 acc;
        #pragma unroll
        for (int i = 0; i < 16; ++i) acc[i] = 0.f;
        #pragma unroll
        for (int ks = 0; ks < 8; ++ks) {
            bf16x8 bf = *(const bf16x8*)(wt + (size_t)c * 128 + ks * 16 + hi * 8);
            acc = __builtin_amdgcn_mfma_f32_32x32x16_bf16(afrag[ks], bf, acc, 0, 0, 0);
        }
        const float bb = bias[c];
        #pragma unroll
        for (int reg = 0; reg < 16; ++reg) {
            int row = (reg & 3) + 8 * (reg >> 2) + 4 * hi;
            int grow = g0 + row;
            if (grow < rows) {
                float x = acc[reg] + bb;
                float gl = 0.5f * x * (1.f + erff(x * 0.70710678118654752f));
                hmid[(size_t)grow * 256 + c] = f2bf(gl);
            }
        }
    }
}

// z2 = zn + hmid @ w2T + b2 ; post-LN ; transposed store fp32
__global__ void __launch_bounds__(256) k_mlp2(
        const u16* __restrict__ hmid, const u16* __restrict__ wt,
        const float* __restrict__ bias, const u16* __restrict__ zn,
        const float* __restrict__ gam, const float* __restrict__ bet,
        float* __restrict__ outp) {
    __shared__ float zt[32][132];
    __shared__ float smu[32], srs[32];
    const int t = threadIdx.x;
    const int g0 = blockIdx.x * 32;
    const int lane = t & 63, wid = t >> 6;
    const int rl = lane & 31, hi = lane >> 5;
    const int rows = BB * NQ;
    int arow = g0 + rl; if (arow > rows - 1) arow = rows - 1;
    const int c = wid * 32 + rl;
    f32x16 acc;
    #pragma unroll
    for (int i = 0; i < 16; ++i) acc[i] = 0.f;
    #pragma unroll
    for (int ks = 0; ks < 16; ++ks) {
        bf16x8 af = *(const bf16x8*)(hmid + (size_t)arow * 256 + ks * 16 + hi * 8);
        bf16x8 bf = *(const bf16x8*)(wt + (size_t)c * 256 + ks * 16 + hi * 8);
        acc = __builtin_amdgcn_mfma_f32_32x32x16_bf16(af, bf, acc, 0, 0, 0);
    }
    const float bb = bias[c];
    #pragma unroll
    for (int reg = 0; reg < 16; ++reg) {
        int row = (reg & 3) + 8 * (reg >> 2) + 4 * hi;
        zt[row][c] = acc[reg] + bb;
    }
    __syncthreads();
    {   // + zn residual
        const int cc = t & 127, rh = t >> 7;
        for (int i = 0; i < 16; ++i) {
            int rr = rh * 16 + i;
            int grow = g0 + rr;
            u16 zv = (grow < rows) ? zn[(size_t)grow * 128 + cc] : (u16)0;
            zt[rr][cc] += bf2f(zv);
        }
    }
    __syncthreads();
    {   // stats, 8 threads/row
        const int r = t >> 3, p = t & 7;
        float sum = 0.f, sq = 0.f;
        for (int j = 0; j < 16; ++j) {
            float v = zt[r][p + 8 * j];
            sum += v; sq += v * v;
        }
        sum += __shfl_xor(sum, 1); sq += __shfl_xor(sq, 1);
        sum += __shfl_xor(sum, 2); sq += __shfl_xor(sq, 2);
        sum += __shfl_xor(sum, 4); sq += __shfl_xor(sq, 4);
        if (p == 0) {
            float mu = sum * (1.f / 128.f);
            float var = sq * (1.f / 128.f) - mu * mu;
            smu[r] = mu; srs[r] = rsqrtf(var + EPSV);
        }
    }
    __syncthreads();
    {   // transposed store
        const int sl = t & 31, du = t >> 5;   // du 0..7
        const int grow = g0 + sl;
        if (grow < rows) {
            const int bn = grow / MM, mm = grow % MM;
            const float mu = smu[sl], rs = srs[sl];
            float* obase = outp + (size_t)bn * 128 * MM + mm;
            for (int it = 0; it < 16; ++it) {
                int dd = it * 8 + du;
                obase[(size_t)dd * MM] = (zt[sl][dd] - mu) * rs * gam[dd] + bet[dd];
            }
        }
    }
}

extern "C" void kernel_launch(void* const* d_in, const int* in_sizes, int n_in,
                              void* d_out, int out_size, void* d_ws, size_t ws_size,
                              hipStream_t stream) {
    const float* q      = (const float*)d_in[0];
    const float* k      = (const float*)d_in[1];
    const float* v      = (const float*)d_in[2];
    const float* skip   = (const float*)d_in[3];
    const float* ln_q_g = (const float*)d_in[4];
    const float* ln_q_b = (const float*)d_in[5];
    const float* wq     = (const float*)d_in[6];
    const float* bq     = (const float*)d_in[7];
    const float* ln_k_g = (const float*)d_in[8];
    const float* ln_k_b = (const float*)d_in[9];
    const float* wk     = (const float*)d_in[10];
    const float* bk     = (const float*)d_in[11];
    const float* ln_v_g = (const float*)d_in[12];
    const float* ln_v_b = (const float*)d_in[13];
    const float* wv     = (const float*)d_in[14];
    const float* bv     = (const float*)d_in[15];
    const float* proj_w = (const float*)d_in[16];
    const float* proj_b = (const float*)d_in[17];
    const float* pre_g  = (const float*)d_in[18];
    const float* pre_b  = (const float*)d_in[19];
    const float* mlp_w1 = (const float*)d_in[20];
    const float* mlp_b1 = (const float*)d_in[21];
    const float* mlp_w2 = (const float*)d_in[22];
    const float* mlp_b2 = (const float*)d_in[23];
    const float* post_g = (const float*)d_in[24];
    const float* post_b = (const float*)d_in[25];

    float* ws   = (float*)d_ws;
    float* outp = (float*)d_out;

    u16* qh   = (u16*)(ws + OFF_QH);
    u16* kh   = (u16*)(ws + OFF_KH);
    u16* vh   = (u16*)(ws + OFF_VH);
    u16* pacc = (u16*)(ws + OFF_PACC);
    float* pl   = ws + OFF_PL;
    u16* a    = (u16*)(ws + OFF_A);
    u16* zn   = (u16*)(ws + OFF_ZN);
    u16* hmid = (u16*)(ws + OFF_HMID);
    u16* wtb  = (u16*)(ws + OFF_WTB);

    k_prep<<<512, 256, 0, stream>>>(wq, wk, wv, proj_w, mlp_w1, mlp_w2, wtb);
    k_lnproj<<<235, 128, 0, stream>>>(q, MM, BB * NQ, ln_q_g, ln_q_b, wtb + WT_Q, bq, QPRESCALE, qh);
    k_lnproj<<<630, 128, 0, stream>>>(k, HWSZ, BB * NK, ln_k_g, ln_k_b, wtb + WT_K, bk, 1.0f, kh);
    k_lnproj<<<630, 128, 0, stream>>>(v, HWSZ, BB * NK, ln_v_g, ln_v_b, wtb + WT_V, bv, 1.0f, vh);
    k_attn_mfma<<<BB * HEADS * NQT256 * KC, 256, 0, stream>>>(qh, kh, vh, pacc, pl);
    k_attn_combine<<<3750, 256, 0, stream>>>(pacc, pl, a);
    k_projskip<<<235, 256, 0, stream>>>(a, wtb + WT_PROJ, proj_b, skip, pre_g, pre_b, zn);
    k_mlp1<<<235, 256, 0, stream>>>(zn, wtb + WT_W1, mlp_b1, hmid);
    k_mlp2<<<235, 256, 0, stream>>>(hmid, wtb + WT_W2, mlp_b2, zn, post_g, post_b, outp);
}

// Round 6
// 160.349 us; speedup vs baseline: 8.9785x; 1.2104x over previous
//
#include <hip/hip_runtime.h>
#include <hip/hip_bf16.h>
#include <math.h>

typedef __attribute__((ext_vector_type(8))) short bf16x8;
typedef __attribute__((ext_vector_type(4))) float f32x4;
typedef __attribute__((ext_vector_type(16))) float f32x16;
typedef unsigned short u16;
typedef unsigned int u32;

#define BB 2
#define NN 6
#define MM 625
#define HWSZ 1680
#define NQ 3750
#define NK 10080
#define HEADS 4
#define EPSV 1e-5f
#define KC 9
#define KCHUNK 1120
#define ITERS 35             // KCHUNK/32
#define NQT256 15            // ceil(3750/256)
#define QPRESCALE 0.25503489f   // (1/sqrt(32)) * log2(e)

// ---- workspace offsets (floats) ----
#define OFF_QH   0          // bf16 960000  u16 -> 480000 fl
#define OFF_KH   480000     // bf16 2580480 u16 -> 1290240 fl
#define OFF_VH   1770240
#define OFF_PACC 3060480    // bf16 2*4*9*3750*32 = 8640000 u16 -> 4320000 fl
#define OFF_PL   7380480    // 270000 fl
#define OFF_A    7650480    // bf16 960000 u16 -> 480000 fl
#define OFF_ZN   8130480
#define OFF_HMID 8610480    // bf16 1920000 u16 -> 960000 fl
#define OFF_WTB  9570480    // 131072 u16 -> 65536 fl ; end 9636016

// u16 offsets inside WTB
#define WT_Q    0
#define WT_K    16384
#define WT_V    32768
#define WT_PROJ 49152
#define WT_W1   65536      // [256][128]
#define WT_W2   98304      // [128][256]

#define VEXP(d, s_) asm("v_exp_f32 %0, %1\n\ts_nop 0" : "=v"(d) : "v"(s_))
#define CVTPK(d, a, b) asm("v_cvt_pk_bf16_f32 %0, %1, %2" : "=v"(d) : "v"(a), "v"(b))

__device__ inline u16 f2bf(float f) {
    __hip_bfloat16 h = __float2bfloat16(f);
    return *reinterpret_cast<u16*>(&h);
}
__device__ inline float bf2f(u16 u) {
    u32 x = ((u32)u) << 16;
    return *reinterpret_cast<float*>(&x);
}
__device__ inline bf16x8 mk_frag(u32 a, u32 b, u32 c, u32 d) {
    union { u32 u[4]; bf16x8 v; } x;
    x.u[0] = a; x.u[1] = b; x.u[2] = c; x.u[3] = d;
    return x.v;
}

// weights -> bf16 transposed
__global__ void __launch_bounds__(256) k_prep(
        const float* __restrict__ wq, const float* __restrict__ wk,
        const float* __restrict__ wv, const float* __restrict__ pw,
        const float* __restrict__ w1, const float* __restrict__ w2,
        u16* __restrict__ wtb) {
    int idx = blockIdx.x * 256 + threadIdx.x;   // 131072 exact
    float v;
    if (idx < 65536) {
        const float* src = (idx < 16384) ? wq : (idx < 32768) ? wk
                         : (idx < 49152) ? wv : pw;
        int r = idx & 16383;
        int c = r >> 7, kk = r & 127;
        v = src[kk * 128 + c];
    } else if (idx < 98304) {
        int r = idx - 65536;
        int c = r >> 7, kk = r & 127;
        v = w1[kk * 256 + c];
    } else {
        int r = idx - 98304;
        int c = r >> 8, kk = r & 255;
        v = w2[kk * 128 + c];
    }
    wtb[idx] = f2bf(v);
}

// LN (over 128 ch, channel-strided input) + MFMA 128x128 projection -> bf16.
__global__ void __launch_bounds__(128) k_lnproj(const float* __restrict__ x, int S, int rows,
        const float* __restrict__ gam, const float* __restrict__ bet,
        const u16* __restrict__ wt, const float* __restrict__ bias,
        float oscale, u16* __restrict__ outp) {
    __shared__ float xs[32][132];
    __shared__ float smu[32], srs[32];
    const int t = threadIdx.x;
    const int g0 = blockIdx.x * 32;
    {   // transposed coalesced load
        const int sl = t & 31, du = t >> 5;
        const int grow = g0 + sl;
        const bool vload = grow < rows;
        const int bn = grow / S, ss = grow % S;
        const float* xbase = x + (size_t)bn * 128 * S + ss;
        for (int it = 0; it < 32; ++it) {
            int dd = it * 4 + du;
            xs[sl][dd] = vload ? xbase[(size_t)dd * S] : 0.f;
        }
    }
    __syncthreads();
    {   // stats, 4 threads/row
        const int r = t >> 2, p = t & 3;
        float sum = 0.f, sq = 0.f;
        for (int j = 0; j < 32; ++j) {
            float v = xs[r][p + 4 * j];
            sum += v; sq += v * v;
        }
        sum += __shfl_xor(sum, 1); sq += __shfl_xor(sq, 1);
        sum += __shfl_xor(sum, 2); sq += __shfl_xor(sq, 2);
        if (p == 0) {
            float mu = sum * (1.f / 128.f);
            float var = sq * (1.f / 128.f) - mu * mu;
            smu[r] = mu;
            srs[r] = rsqrtf(var + EPSV);
        }
    }
    __syncthreads();
    {   // normalize in LDS
        const float gv = gam[t], bv = bet[t];
        for (int rr = 0; rr < 32; ++rr)
            xs[rr][t] = (xs[rr][t] - smu[rr]) * srs[rr] * gv + bv;
    }
    __syncthreads();
    // MFMA GEMM: wave wid covers cols wid*64..+63
    const int lane = t & 63, wid = t >> 6;
    const int rl = lane & 31, hi = lane >> 5;
    bf16x8 afrag[8];
    #pragma unroll
    for (int ks = 0; ks < 8; ++ks) {
        float4 u = *(const float4*)&xs[rl][ks * 16 + hi * 8];
        float4 w = *(const float4*)&xs[rl][ks * 16 + hi * 8 + 4];
        u32 d0, d1, d2, d3;
        CVTPK(d0, u.x, u.y);
        CVTPK(d1, u.z, u.w);
        CVTPK(d2, w.x, w.y);
        CVTPK(d3, w.z, w.w);
        afrag[ks] = mk_frag(d0, d1, d2, d3);
    }
    #pragma unroll
    for (int tile = 0; tile < 2; ++tile) {
        const int c = wid * 64 + tile * 32 + rl;
        f32x16 acc;
        #pragma unroll
        for (int i = 0; i < 16; ++i) acc[i] = 0.f;
        #pragma unroll
        for (int ks = 0; ks < 8; ++ks) {
            bf16x8 bfrag = *(const bf16x8*)(wt + (size_t)c * 128 + ks * 16 + hi * 8);
            acc = __builtin_amdgcn_mfma_f32_32x32x16_bf16(afrag[ks], bfrag, acc, 0, 0, 0);
        }
        const float bb = bias[c];
        #pragma unroll
        for (int reg = 0; reg < 16; ++reg) {
            int row = (reg & 3) + 8 * (reg >> 2) + 4 * hi;
            int grow = g0 + row;
            if (grow < rows) outp[(size_t)grow * 128 + c] = f2bf((acc[reg] + bb) * oscale);
        }
    }
}

// MFMA flash attention partial: 32x32 swapped-QK^T, in-register softmax,
// 2 q-tiles/wave, cooperative coalesced K+V staging, double-buffered LDS,
// one barrier per iter.
__global__ void __launch_bounds__(256, 3) k_attn_mfma(
        const u16* __restrict__ qh, const u16* __restrict__ kh, const u16* __restrict__ vh,
        u16* __restrict__ pacc, float* __restrict__ pl) {
    __shared__ __align__(16) u16 Ks[2][32 * 40];   // K tile: [key 32][dh 32, stride 40]
    __shared__ __align__(16) u16 Vs[2][32 * 40];   // V^T tile: [dh 32][key 32, stride 40]
    const int t = threadIdx.x;
    const int lane = t & 63, wid = t >> 6;
    const int rl = lane & 31, hi = lane >> 5;
    int bid = blockIdx.x;
    const int kc = bid % KC; bid /= KC;
    const int qt = bid % NQT256; bid /= NQT256;
    const int h = bid % HEADS;
    const int b = bid / HEADS;
    const int q0A = qt * 256 + wid * 32;
    const int q0B = q0A + 128;

    int qrowA = q0A + rl; if (qrowA > NQ - 1) qrowA = NQ - 1;
    int qrowB = q0B + rl; if (qrowB > NQ - 1) qrowB = NQ - 1;
    const u16* qpA = qh + ((size_t)b * NQ + qrowA) * 128 + h * 32;
    const u16* qpB = qh + ((size_t)b * NQ + qrowB) * 128 + h * 32;
    const bf16x8 qfA0 = *(const bf16x8*)(qpA + hi * 8);
    const bf16x8 qfA1 = *(const bf16x8*)(qpA + 16 + hi * 8);
    const bf16x8 qfB0 = *(const bf16x8*)(qpB + hi * 8);
    const bf16x8 qfB1 = *(const bf16x8*)(qpB + 16 + hi * 8);

    const int kstart = kc * KCHUNK;
    // cooperative staging mapping: thread owns (key, 4-dh group), 8B contiguous
    const int skey = t >> 3, sdh = (t & 7) * 4;
    const u16* kgp = kh + ((size_t)b * NK + kstart + skey) * 128 + h * 32 + sdh;
    const u16* vgp = vh + ((size_t)b * NK + kstart + skey) * 128 + h * 32 + sdh;

    f32x16 accA, accB, zero16;
    #pragma unroll
    for (int i = 0; i < 16; ++i) { accA[i] = 0.f; accB[i] = 0.f; zero16[i] = 0.f; }
    f32x4 lsA = {0.f, 0.f, 0.f, 0.f}, lsB = {0.f, 0.f, 0.f, 0.f};

    // prologue: stage tile0, hold tile1 in regs
    {
        ushort4 k0v = *(const ushort4*)kgp;
        ushort4 v0v = *(const ushort4*)vgp;
        *(ushort4*)&Ks[0][skey * 40 + sdh] = k0v;
        Vs[0][(sdh + 0) * 40 + skey] = v0v.x;
        Vs[0][(sdh + 1) * 40 + skey] = v0v.y;
        Vs[0][(sdh + 2) * 40 + skey] = v0v.z;
        Vs[0][(sdh + 3) * 40 + skey] = v0v.w;
    }
    ushort4 kheld = *(const ushort4*)(kgp + 32 * 128);
    ushort4 vheld = *(const ushort4*)(vgp + 32 * 128);
    __syncthreads();

    for (int ii = 0; ii < ITERS; ++ii) {
        const int cur = ii & 1;
        // stage tile ii+1 into the other buffer (garbage on last iter, never read)
        *(ushort4*)&Ks[cur ^ 1][skey * 40 + sdh] = kheld;
        {
            u16* vs = &Vs[cur ^ 1][sdh * 40 + skey];
            vs[0] = vheld.x; vs[40] = vheld.y; vs[80] = vheld.z; vs[120] = vheld.w;
        }
        // issue loads for tile ii+2
        int t2 = (ii + 2 < ITERS) ? (ii + 2) : 0;
        kheld = *(const ushort4*)(kgp + (size_t)t2 * 32 * 128);
        vheld = *(const ushort4*)(vgp + (size_t)t2 * 32 * 128);

        // K fragments from LDS (staged last iter)
        const bf16x8 kf0 = *(const bf16x8*)&Ks[cur][rl * 40 + hi * 8];
        const bf16x8 kf1 = *(const bf16x8*)&Ks[cur][rl * 40 + 16 + hi * 8];

        // QK^T for both q-tiles (shared K-fragments)
        __builtin_amdgcn_s_setprio(1);
        f32x16 sA = __builtin_amdgcn_mfma_f32_32x32x16_bf16(kf0, qfA0, zero16, 0, 0, 0);
        sA = __builtin_amdgcn_mfma_f32_32x32x16_bf16(kf1, qfA1, sA, 0, 0, 0);
        f32x16 sB = __builtin_amdgcn_mfma_f32_32x32x16_bf16(kf0, qfB0, zero16, 0, 0, 0);
        sB = __builtin_amdgcn_mfma_f32_32x32x16_bf16(kf1, qfB1, sB, 0, 0, 0);
        __builtin_amdgcn_s_setprio(0);

        // softmax numerators (fixed max=0; Q pre-scaled by SCALE*log2e)
        u32 a0, a1, a2, a3, a4, a5, a6, a7;
        u32 b0, b1, b2, b3, b4, b5, b6, b7;
        {
            float e0, e1, e2, e3;
            VEXP(e0, sA[0]);  VEXP(e1, sA[1]);  VEXP(e2, sA[2]);  VEXP(e3, sA[3]);
            CVTPK(a0, e0, e1); CVTPK(a1, e2, e3);
            lsA += (f32x4){e0, e1, e2, e3};
            VEXP(e0, sA[4]);  VEXP(e1, sA[5]);  VEXP(e2, sA[6]);  VEXP(e3, sA[7]);
            CVTPK(a2, e0, e1); CVTPK(a3, e2, e3);
            lsA += (f32x4){e0, e1, e2, e3};
            VEXP(e0, sA[8]);  VEXP(e1, sA[9]);  VEXP(e2, sA[10]); VEXP(e3, sA[11]);
            CVTPK(a4, e0, e1); CVTPK(a5, e2, e3);
            lsA += (f32x4){e0, e1, e2, e3};
            VEXP(e0, sA[12]); VEXP(e1, sA[13]); VEXP(e2, sA[14]); VEXP(e3, sA[15]);
            CVTPK(a6, e0, e1); CVTPK(a7, e2, e3);
            lsA += (f32x4){e0, e1, e2, e3};
            VEXP(e0, sB[0]);  VEXP(e1, sB[1]);  VEXP(e2, sB[2]);  VEXP(e3, sB[3]);
            CVTPK(b0, e0, e1); CVTPK(b1, e2, e3);
            lsB += (f32x4){e0, e1, e2, e3};
            VEXP(e0, sB[4]);  VEXP(e1, sB[5]);  VEXP(e2, sB[6]);  VEXP(e3, sB[7]);
            CVTPK(b2, e0, e1); CVTPK(b3, e2, e3);
            lsB += (f32x4){e0, e1, e2, e3};
            VEXP(e0, sB[8]);  VEXP(e1, sB[9]);  VEXP(e2, sB[10]); VEXP(e3, sB[11]);
            CVTPK(b4, e0, e1); CVTPK(b5, e2, e3);
            lsB += (f32x4){e0, e1, e2, e3};
            VEXP(e0, sB[12]); VEXP(e1, sB[13]); VEXP(e2, sB[14]); VEXP(e3, sB[15]);
            CVTPK(b6, e0, e1); CVTPK(b7, e2, e3);
            lsB += (f32x4){e0, e1, e2, e3};
        }
        asm("v_permlane32_swap_b32 %0, %1" : "+v"(a0), "+v"(a2));
        asm("v_permlane32_swap_b32 %0, %1" : "+v"(a1), "+v"(a3));
        asm("v_permlane32_swap_b32 %0, %1" : "+v"(a4), "+v"(a6));
        asm("v_permlane32_swap_b32 %0, %1" : "+v"(a5), "+v"(a7));
        asm("v_permlane32_swap_b32 %0, %1" : "+v"(b0), "+v"(b2));
        asm("v_permlane32_swap_b32 %0, %1" : "+v"(b1), "+v"(b3));
        asm("v_permlane32_swap_b32 %0, %1" : "+v"(b4), "+v"(b6));
        asm("v_permlane32_swap_b32 %0, %1" : "+v"(b5), "+v"(b7));
        const bf16x8 pA0 = mk_frag(a0, a1, a2, a3);
        const bf16x8 pA1 = mk_frag(a4, a5, a6, a7);
        const bf16x8 pB0 = mk_frag(b0, b1, b2, b3);
        const bf16x8 pB1 = mk_frag(b4, b5, b6, b7);

        // PV: V-fragments read once, feed both q-tiles
        const bf16x8 vf0 = *(const bf16x8*)&Vs[cur][rl * 40 + hi * 8];
        const bf16x8 vf1 = *(const bf16x8*)&Vs[cur][rl * 40 + 16 + hi * 8];
        __builtin_amdgcn_s_setprio(1);
        accA = __builtin_amdgcn_mfma_f32_32x32x16_bf16(pA0, vf0, accA, 0, 0, 0);
        accA = __builtin_amdgcn_mfma_f32_32x32x16_bf16(pA1, vf1, accA, 0, 0, 0);
        accB = __builtin_amdgcn_mfma_f32_32x32x16_bf16(pB0, vf0, accB, 0, 0, 0);
        accB = __builtin_amdgcn_mfma_f32_32x32x16_bf16(pB1, vf1, accB, 0, 0, 0);
        __builtin_amdgcn_s_setprio(0);

        __syncthreads();   // staged buf ready for next iter; cur free for overwrite
    }

    float lsumA = (lsA[0] + lsA[1]) + (lsA[2] + lsA[3]);
    float lsumB = (lsB[0] + lsB[1]) + (lsB[2] + lsB[3]);
    float ltotA = lsumA + __shfl_xor(lsumA, 32);
    float ltotB = lsumB + __shfl_xor(lsumB, 32);

    const int pi = (b * HEADS + h) * KC + kc;
    #pragma unroll
    for (int reg = 0; reg < 16; ++reg) {
        int qloc = (reg & 3) + 8 * (reg >> 2) + 4 * hi;
        int qqA = q0A + qloc;
        int qqB = q0B + qloc;
        if (qqA < NQ) pacc[((size_t)pi * NQ + qqA) * 32 + rl] = f2bf(accA[reg]);
        if (qqB < NQ) pacc[((size_t)pi * NQ + qqB) * 32 + rl] = f2bf(accB[reg]);
    }
    if (hi == 0) {
        int qqA = q0A + rl, qqB = q0B + rl;
        if (qqA < NQ) pl[(size_t)pi * NQ + qqA] = ltotA;
        if (qqB < NQ) pl[(size_t)pi * NQ + qqB] = ltotB;
    }
}

__global__ void __launch_bounds__(256) k_attn_combine(const u16* __restrict__ pacc,
        const float* __restrict__ pl, u16* __restrict__ a) {
    const int idx = blockIdx.x * 256 + threadIdx.x;   // B*H*NQ*32, exact
    const int j = idx & 31;
    const int qq = (idx >> 5) % NQ;
    const int bh = idx / (32 * NQ);
    const int b = bh / HEADS, h = bh % HEADS;
    float L = 0.f, val = 0.f;
    #pragma unroll
    for (int kc = 0; kc < KC; ++kc) {
        size_t pi = (size_t)(bh * KC + kc) * NQ + qq;
        L += pl[pi];
        val += bf2f(pacc[pi * 32 + j]);
    }
    a[((size_t)b * NQ + qq) * 128 + h * 32 + j] = f2bf(val / L);
}

// z0 = a @ projT + b ; + skip ; pre-LN -> zn (bf16)
__global__ void __launch_bounds__(256) k_projskip(
        const u16* __restrict__ a, const u16* __restrict__ wt,
        const float* __restrict__ bias, const float* __restrict__ skip,
        const float* __restrict__ gam, const float* __restrict__ bet,
        u16* __restrict__ zn) {
    __shared__ float zs[32][132];
    __shared__ float smu[32], srs[32];
    const int t = threadIdx.x;
    const int g0 = blockIdx.x * 32;
    const int lane = t & 63, wid = t >> 6;
    const int rl = lane & 31, hi = lane >> 5;
    const int rows = BB * NQ;
    int arow = g0 + rl; if (arow > rows - 1) arow = rows - 1;
    const int c = wid * 32 + rl;
    f32x16 acc;
    #pragma unroll
    for (int i = 0; i < 16; ++i) acc[i] = 0.f;
    #pragma unroll
    for (int ks = 0; ks < 8; ++ks) {
        bf16x8 af = *(const bf16x8*)(a + (size_t)arow * 128 + ks * 16 + hi * 8);
        bf16x8 bf = *(const bf16x8*)(wt + (size_t)c * 128 + ks * 16 + hi * 8);
        acc = __builtin_amdgcn_mfma_f32_32x32x16_bf16(af, bf, acc, 0, 0, 0);
    }
    const float bb = bias[c];
    #pragma unroll
    for (int reg = 0; reg < 16; ++reg) {
        int row = (reg & 3) + 8 * (reg >> 2) + 4 * hi;
        zs[row][c] = acc[reg] + bb;
    }
    __syncthreads();
    {   // skip add (channel-strided)
        const int sl = t & 31, du = t >> 5;   // du 0..7
        const int grow = g0 + sl;
        if (grow < rows) {
            const int bn = grow / MM, mm = grow % MM;
            const float* sbase = skip + (size_t)bn * 128 * MM + mm;
            for (int it = 0; it < 16; ++it) {
                int dd = it * 8 + du;
                zs[sl][dd] += sbase[(size_t)dd * MM];
            }
        }
    }
    __syncthreads();
    {   // stats, 8 threads/row
        const int r = t >> 3, p = t & 7;
        float sum = 0.f, sq = 0.f;
        for (int j = 0; j < 16; ++j) {
            float v = zs[r][p + 8 * j];
            sum += v; sq += v * v;
        }
        sum += __shfl_xor(sum, 1); sq += __shfl_xor(sq, 1);
        sum += __shfl_xor(sum, 2); sq += __shfl_xor(sq, 2);
        sum += __shfl_xor(sum, 4); sq += __shfl_xor(sq, 4);
        if (p == 0) {
            float mu = sum * (1.f / 128.f);
            float var = sq * (1.f / 128.f) - mu * mu;
            smu[r] = mu; srs[r] = rsqrtf(var + EPSV);
        }
    }
    __syncthreads();
    {
        const int cc = t & 127, rh = t >> 7;
        const float gv = gam[cc], bv = bet[cc];
        for (int i = 0; i < 16; ++i) {
            int rr = rh * 16 + i;
            int grow = g0 + rr;
            if (grow < rows)
                zn[(size_t)grow * 128 + cc] = f2bf((zs[rr][cc] - smu[rr]) * srs[rr] * gv + bv);
        }
    }
}

// hmid = gelu(zn @ w1T + b1) -> bf16
__global__ void __launch_bounds__(256) k_mlp1(
        const u16* __restrict__ zn, const u16* __restrict__ wt,
        const float* __restrict__ bias, u16* __restrict__ hmid) {
    const int t = threadIdx.x;
    const int g0 = blockIdx.x * 32;
    const int lane = t & 63, wid = t >> 6;
    const int rl = lane & 31, hi = lane >> 5;
    const int rows = BB * NQ;
    int arow = g0 + rl; if (arow > rows - 1) arow = rows - 1;
    bf16x8 afrag[8];
    #pragma unroll
    for (int ks = 0; ks < 8; ++ks)
        afrag[ks] = *(const bf16x8*)(zn + (size_t)arow * 128 + ks * 16 + hi * 8);
    #pragma unroll
    for (int tile = 0; tile < 2; ++tile) {
        const int c = wid * 64 + tile * 32 + rl;
        f32x16 acc;
        #pragma unroll
        for (int i = 0; i < 16; ++i) acc[i] = 0.f;
        #pragma unroll
        for (int ks = 0; ks < 8; ++ks) {
            bf16x8 bf = *(const bf16x8*)(wt + (size_t)c * 128 + ks * 16 + hi * 8);
            acc = __builtin_amdgcn_mfma_f32_32x32x16_bf16(afrag[ks], bf, acc, 0, 0, 0);
        }
        const float bb = bias[c];
        #pragma unroll
        for (int reg = 0; reg < 16; ++reg) {
            int row = (reg & 3) + 8 * (reg >> 2) + 4 * hi;
            int grow = g0 + row;
            if (grow < rows) {
                float x = acc[reg] + bb;
                float gl = 0.5f * x * (1.f + erff(x * 0.70710678118654752f));
                hmid[(size_t)grow * 256 + c] = f2bf(gl);
            }
        }
    }
}

// z2 = zn + hmid @ w2T + b2 ; post-LN ; transposed store fp32
__global__ void __launch_bounds__(256) k_mlp2(
        const u16* __restrict__ hmid, const u16* __restrict__ wt,
        const float* __restrict__ bias, const u16* __restrict__ zn,
        const float* __restrict__ gam, const float* __restrict__ bet,
        float* __restrict__ outp) {
    __shared__ float zt[32][132];
    __shared__ float smu[32], srs[32];
    const int t = threadIdx.x;
    const int g0 = blockIdx.x * 32;
    const int lane = t & 63, wid = t >> 6;
    const int rl = lane & 31, hi = lane >> 5;
    const int rows = BB * NQ;
    int arow = g0 + rl; if (arow > rows - 1) arow = rows - 1;
    const int c = wid * 32 + rl;
    f32x16 acc;
    #pragma unroll
    for (int i = 0; i < 16; ++i) acc[i] = 0.f;
    #pragma unroll
    for (int ks = 0; ks < 16; ++ks) {
        bf16x8 af = *(const bf16x8*)(hmid + (size_t)arow * 256 + ks * 16 + hi * 8);
        bf16x8 bf = *(const bf16x8*)(wt + (size_t)c * 256 + ks * 16 + hi * 8);
        acc = __builtin_amdgcn_mfma_f32_32x32x16_bf16(af, bf, acc, 0, 0, 0);
    }
    const float bb = bias[c];
    #pragma unroll
    for (int reg = 0; reg < 16; ++reg) {
        int row = (reg & 3) + 8 * (reg >> 2) + 4 * hi;
        zt[row][c] = acc[reg] + bb;
    }
    __syncthreads();
    {   // + zn residual
        const int cc = t & 127, rh = t >> 7;
        for (int i = 0; i < 16; ++i) {
            int rr = rh * 16 + i;
            int grow = g0 + rr;
            u16 zv = (grow < rows) ? zn[(size_t)grow * 128 + cc] : (u16)0;
            zt[rr][cc] += bf2f(zv);
        }
    }
    __syncthreads();
    {   // stats, 8 threads/row
        const int r = t >> 3, p = t & 7;
        float sum = 0.f, sq = 0.f;
        for (int j = 0; j < 16; ++j) {
            float v = zt[r][p + 8 * j];
            sum += v; sq += v * v;
        }
        sum += __shfl_xor(sum, 1); sq += __shfl_xor(sq, 1);
        sum += __shfl_xor(sum, 2); sq += __shfl_xor(sq, 2);
        sum += __shfl_xor(sum, 4); sq += __shfl_xor(sq, 4);
        if (p == 0) {
            float mu = sum * (1.f / 128.f);
            float var = sq * (1.f / 128.f) - mu * mu;
            smu[r] = mu; srs[r] = rsqrtf(var + EPSV);
        }
    }
    __syncthreads();
    {   // transposed store
        const int sl = t & 31, du = t >> 5;   // du 0..7
        const int grow = g0 + sl;
        if (grow < rows) {
            const int bn = grow / MM, mm = grow % MM;
            const float mu = smu[sl], rs = srs[sl];
            float* obase = outp + (size_t)bn * 128 * MM + mm;
            for (int it = 0; it < 16; ++it) {
                int dd = it * 8 + du;
                obase[(size_t)dd * MM] = (zt[sl][dd] - mu) * rs * gam[dd] + bet[dd];
            }
        }
    }
}

extern "C" void kernel_launch(void* const* d_in, const int* in_sizes, int n_in,
                              void* d_out, int out_size, void* d_ws, size_t ws_size,
                              hipStream_t stream) {
    const float* q      = (const float*)d_in[0];
    const float* k      = (const float*)d_in[1];
    const float* v      = (const float*)d_in[2];
    const float* skip   = (const float*)d_in[3];
    const float* ln_q_g = (const float*)d_in[4];
    const float* ln_q_b = (const float*)d_in[5];
    const float* wq     = (const float*)d_in[6];
    const float* bq     = (const float*)d_in[7];
    const float* ln_k_g = (const float*)d_in[8];
    const float* ln_k_b = (const float*)d_in[9];
    const float* wk     = (const float*)d_in[10];
    const float* bk     = (const float*)d_in[11];
    const float* ln_v_g = (const float*)d_in[12];
    const float* ln_v_b = (const float*)d_in[13];
    const float* wv     = (const float*)d_in[14];
    const float* bv     = (const float*)d_in[15];
    const float* proj_w = (const float*)d_in[16];
    const float* proj_b = (const float*)d_in[17];
    const float* pre_g  = (const float*)d_in[18];
    const float* pre_b  = (const float*)d_in[19];
    const float* mlp_w1 = (const float*)d_in[20];
    const float* mlp_b1 = (const float*)d_in[21];
    const float* mlp_w2 = (const float*)d_in[22];
    const float* mlp_b2 = (const float*)d_in[23];
    const float* post_g = (const float*)d_in[24];
    const float* post_b = (const float*)d_in[25];

    float* ws   = (float*)d_ws;
    float* outp = (float*)d_out;

    u16* qh   = (u16*)(ws + OFF_QH);
    u16* kh   = (u16*)(ws + OFF_KH);
    u16* vh   = (u16*)(ws + OFF_VH);
    u16* pacc = (u16*)(ws + OFF_PACC);
    float* pl   = ws + OFF_PL;
    u16* a    = (u16*)(ws + OFF_A);
    u16* zn   = (u16*)(ws + OFF_ZN);
    u16* hmid = (u16*)(ws + OFF_HMID);
    u16* wtb  = (u16*)(ws + OFF_WTB);

    k_prep<<<512, 256, 0, stream>>>(wq, wk, wv, proj_w, mlp_w1, mlp_w2, wtb);
    k_lnproj<<<235, 128, 0, stream>>>(q, MM, BB * NQ, ln_q_g, ln_q_b, wtb + WT_Q, bq, QPRESCALE, qh);
    k_lnproj<<<630, 128, 0, stream>>>(k, HWSZ, BB * NK, ln_k_g, ln_k_b, wtb + WT_K, bk, 1.0f, kh);
    k_lnproj<<<630, 128, 0, stream>>>(v, HWSZ, BB * NK, ln_v_g, ln_v_b, wtb + WT_V, bv, 1.0f, vh);
    k_attn_mfma<<<BB * HEADS * NQT256 * KC, 256, 0, stream>>>(qh, kh, vh, pacc, pl);
    k_attn_combine<<<3750, 256, 0, stream>>>(pacc, pl, a);
    k_projskip<<<235, 256, 0, stream>>>(a, wtb + WT_PROJ, proj_b, skip, pre_g, pre_b, zn);
    k_mlp1<<<235, 256, 0, stream>>>(zn, wtb + WT_W1, mlp_b1, hmid);
    k_mlp2<<<235, 256, 0, stream>>>(hmid, wtb + WT_W2, mlp_b2, zn, post_g, post_b, outp);
}